// Round 1
// baseline (3473.713 us; speedup 1.0000x reference)
//
#include <hip/hip_runtime.h>
#include <hip/hip_bf16.h>
#include <math.h>

#define KG 4   // dst nodes per block in kron kernel

// ---------------------------------------------------------------- helpers
__device__ __forceinline__ void blockSum2(float& s1, float& s2, float* red) {
    // 256-thread block: butterfly within wave, then cross-wave via LDS red[8]
    #pragma unroll
    for (int off = 32; off > 0; off >>= 1) {
        s1 += __shfl_xor(s1, off);
        s2 += __shfl_xor(s2, off);
    }
    int lane = threadIdx.x & 63, wid = threadIdx.x >> 6;
    if (lane == 0) { red[wid] = s1; red[4 + wid] = s2; }
    __syncthreads();
    s1 = red[0] + red[1] + red[2] + red[3];
    s2 = red[4] + red[5] + red[6] + red[7];
}

__device__ __forceinline__ float sigmoidf(float x) { return 1.0f / (1.0f + expf(-x)); }

// ---------------------------------------------------------------- npj = relu(LN(nf@Wp + bp))
__global__ __launch_bounds__(64) void npj_kernel(
    const float* __restrict__ nf, const float* __restrict__ Wp,
    const float* __restrict__ bp, const float* __restrict__ gp,
    const float* __restrict__ betap, float* __restrict__ npj, int V)
{
    int v = blockIdx.x;
    int j = threadIdx.x;
    float acc = 0.f;
    if (j < 20) {
        acc = bp[j];
        const float* row = nf + (size_t)v * 256;
        #pragma unroll 8
        for (int i = 0; i < 256; ++i) acc += row[i] * Wp[i * 20 + j];
    }
    float x = (j < 20) ? acc : 0.f;
    float s1 = x, s2 = x * x;
    #pragma unroll
    for (int off = 32; off > 0; off >>= 1) {
        s1 += __shfl_xor(s1, off);
        s2 += __shfl_xor(s2, off);
    }
    float mu = s1 * (1.0f / 20.0f);
    float var = s2 * (1.0f / 20.0f) - mu * mu;
    if (j < 20) {
        float y = (acc - mu) * rsqrtf(var + 1e-5f) * gp[j] + betap[j];
        npj[(size_t)v * 20 + j] = fmaxf(y, 0.f);
    }
}

// ---------------------------------------------------------------- CSR build
__global__ __launch_bounds__(256) void deg_kernel(const int* __restrict__ dst, int* __restrict__ deg, int E) {
    int e = blockIdx.x * 256 + threadIdx.x;
    if (e < E) atomicAdd(&deg[dst[e]], 1);
}

__global__ __launch_bounds__(1024) void scan_kernel(const int* __restrict__ deg, int* __restrict__ row, int V) {
    __shared__ int buf[1024];
    __shared__ int carry_sh;
    int t = threadIdx.x;
    if (t == 0) carry_sh = 0;
    __syncthreads();
    for (int base = 0; base < V; base += 1024) {
        int i = base + t;
        int v = (i < V) ? deg[i] : 0;
        buf[t] = v;
        __syncthreads();
        int val = v;
        for (int s = 1; s < 1024; s <<= 1) {
            int add = (t >= s) ? buf[t - s] : 0;
            __syncthreads();
            val += add;
            buf[t] = val;
            __syncthreads();
        }
        int c = carry_sh;
        if (i < V) row[i + 1] = c + val;
        __syncthreads();
        if (t == 1023) carry_sh = c + val;
        __syncthreads();
    }
    if (t == 0) row[0] = 0;
}

__global__ __launch_bounds__(256) void scatter_kernel(
    const int* __restrict__ dst, const int* __restrict__ row,
    int* __restrict__ cnt, int* __restrict__ eorder, int E)
{
    int e = blockIdx.x * 256 + threadIdx.x;
    if (e < E) {
        int d = dst[e];
        int pos = row[d] + atomicAdd(&cnt[d], 1);
        eorder[pos] = e;
    }
}

// ---------------------------------------------------------------- edge logits = relu([nf[dst],nf[src]]@We + be)
__global__ __launch_bounds__(256) void logit_kernel(
    const float* __restrict__ nf, const int* __restrict__ src, const int* __restrict__ dst,
    const float* __restrict__ We, const float* __restrict__ be,
    float* __restrict__ logit, int E)
{
    int wid = threadIdx.x >> 6, lane = threadIdx.x & 63;
    int e = blockIdx.x * 4 + wid;
    if (e >= E) return;
    int d = dst[e], s = src[e];
    // lanes 0..31 cover he[0..255] = nf[dst]; lanes 32..63 cover he[256..511] = nf[src]
    const float* row = (lane < 32) ? (nf + (size_t)d * 256) : (nf + (size_t)s * 256 - 256);
    int i = lane * 8;
    float4 x0 = *(const float4*)(row + i);
    float4 x1 = *(const float4*)(row + i + 4);
    float4 w0 = *(const float4*)(We + i);
    float4 w1 = *(const float4*)(We + i + 4);
    float sum = x0.x * w0.x + x0.y * w0.y + x0.z * w0.z + x0.w * w0.w
              + x1.x * w1.x + x1.y * w1.y + x1.z * w1.z + x1.w * w1.w;
    #pragma unroll
    for (int off = 32; off > 0; off >>= 1) sum += __shfl_xor(sum, off);
    if (lane == 0) logit[e] = fmaxf(sum + be[0], 0.f);
}

// ---------------------------------------------------------------- kron branch (CSR-grouped by dst)
// Per block: KG dst nodes. T_v[a][o] = sum_k npj[v][k]*Wk[a*20+k][o] (bf16 in LDS),
// then per edge y[o] = bk[o] + sum_a npj[src][a]*T[a][o], LN+relu, register-accumulate kron_feat.
__global__ __launch_bounds__(256) void kron_kernel(
    const float* __restrict__ npj, const int* __restrict__ srcArr,
    const int* __restrict__ eorder, const int* __restrict__ rowPtr,
    const float* __restrict__ Wk, const float* __restrict__ bk,
    const float* __restrict__ gkv, const float* __restrict__ betak,
    float* __restrict__ kron_feat, int V)
{
    __shared__ __hip_bfloat16 T[KG * 20 * 256];   // 40 KB
    __shared__ float dsh[KG * 20];
    __shared__ float sEdge[20];
    __shared__ float red[8];
    int t = threadIdx.x;
    int v0 = blockIdx.x * KG;

    if (t < KG * 20) {
        int g = t / 20, k = t % 20;
        int v = v0 + g;
        dsh[t] = (v < V) ? npj[(size_t)v * 20 + k] : 0.f;
    }
    __syncthreads();

    float dreg[KG][20];
    #pragma unroll
    for (int g = 0; g < KG; ++g)
        #pragma unroll
        for (int k = 0; k < 20; ++k) dreg[g][k] = dsh[g * 20 + k];

    // T compute: per a, load one Wk column-slab (20 rows) into regs, FMA into KG outputs
    for (int a = 0; a < 20; ++a) {
        float w[20];
        #pragma unroll
        for (int k = 0; k < 20; ++k) w[k] = Wk[(size_t)(a * 20 + k) * 256 + t];
        #pragma unroll
        for (int g = 0; g < KG; ++g) {
            float s = 0.f;
            #pragma unroll
            for (int k = 0; k < 20; ++k) s += dreg[g][k] * w[k];
            T[(g * 20 + a) * 256 + t] = __float2bfloat16(s);
        }
    }
    __syncthreads();

    float bko = bk[t], gko = gkv[t], beko = betak[t];

    for (int g = 0; g < KG; ++g) {
        int v = v0 + g;
        if (v >= V) break;
        float Tr[20];
        #pragma unroll
        for (int a = 0; a < 20; ++a) Tr[a] = __bfloat162float(T[(g * 20 + a) * 256 + t]);
        float acc = 0.f;
        int e0 = rowPtr[v], e1 = rowPtr[v + 1];
        for (int p = e0; p < e1; ++p) {
            int e = eorder[p];
            int sv = srcArr[e];
            __syncthreads();   // protect sEdge/red reuse from previous iteration
            if (t < 20) sEdge[t] = npj[(size_t)sv * 20 + t];
            __syncthreads();
            float y = bko;
            #pragma unroll
            for (int a = 0; a < 20; ++a) y += sEdge[a] * Tr[a];
            float s1 = y, s2 = y * y;
            blockSum2(s1, s2, red);
            float mu = s1 * (1.0f / 256.0f);
            float var = s2 * (1.0f / 256.0f) - mu * mu;
            float yn = (y - mu) * rsqrtf(var + 1e-5f) * gko + beko;
            acc += fmaxf(yn, 0.f);
        }
        kron_feat[(size_t)v * 256 + t] = acc;
    }
}

// ---------------------------------------------------------------- generic 64x64 tiled GEMM
// C[M,256] = [A1 | A2][M,K] @ B[K,256] + bias  (A row stride 256 for both halves, ksplit = cols in A1)
__global__ __launch_bounds__(256) void gemm64_kernel(
    const float* __restrict__ A1, const float* __restrict__ A2, int ksplit, int K,
    const float* __restrict__ B, const float* __restrict__ bias,
    float* __restrict__ C, int M)
{
    __shared__ float As[16][68];
    __shared__ float Bs[16][68];
    int t = threadIdx.x;
    int tx = t & 15, ty = t >> 4;
    int n0 = blockIdx.x * 64, c0 = blockIdx.y * 64;
    float acc[4][4] = {};
    int lnode = t >> 2;
    int lkq = (t & 3) * 4;
    int lkr = t >> 4;
    int lc = (t & 15) * 4;

    for (int k0 = 0; k0 < K; k0 += 16) {
        int gn = n0 + lnode;
        float4 av = make_float4(0.f, 0.f, 0.f, 0.f);
        if (gn < M) {
            int kk = k0 + lkq;
            const float* srcp = (kk < ksplit) ? (A1 + (size_t)gn * 256 + kk)
                                              : (A2 + (size_t)gn * 256 + (kk - ksplit));
            av = *(const float4*)srcp;
        }
        As[lkq + 0][lnode] = av.x; As[lkq + 1][lnode] = av.y;
        As[lkq + 2][lnode] = av.z; As[lkq + 3][lnode] = av.w;
        float4 bv = *(const float4*)(B + (size_t)(k0 + lkr) * 256 + c0 + lc);
        *(float4*)&Bs[lkr][lc] = bv;
        __syncthreads();
        #pragma unroll
        for (int kk = 0; kk < 16; ++kk) {
            float a[4], b[4];
            *(float4*)a = *(const float4*)&As[kk][tx * 4];
            *(float4*)b = *(const float4*)&Bs[kk][ty * 4];
            #pragma unroll
            for (int i = 0; i < 4; ++i)
                #pragma unroll
                for (int j = 0; j < 4; ++j)
                    acc[i][j] += a[i] * b[j];
        }
        __syncthreads();
    }
    float bvals[4];
    *(float4*)bvals = *(const float4*)(bias + c0 + ty * 4);
    #pragma unroll
    for (int i = 0; i < 4; ++i) {
        int gn = n0 + tx * 4 + i;
        if (gn < M) {
            float4 o = make_float4(acc[i][0] + bvals[0], acc[i][1] + bvals[1],
                                   acc[i][2] + bvals[2], acc[i][3] + bvals[3]);
            *(float4*)(C + (size_t)gn * 256 + c0 + ty * 4) = o;
        }
    }
}

// ---------------------------------------------------------------- attention + context
__global__ __launch_bounds__(256) void ctx_kernel(
    const float* __restrict__ hv, const float* __restrict__ logit,
    const int* __restrict__ srcArr, const int* __restrict__ eorder,
    const int* __restrict__ rowPtr, float* __restrict__ ctx, int V)
{
    int v = blockIdx.x;
    int t = threadIdx.x;
    int e0 = rowPtr[v], e1 = rowPtr[v + 1];
    float m = -1e30f;
    for (int p = e0; p < e1; ++p) m = fmaxf(m, logit[eorder[p]]);
    float denom = 0.f;
    for (int p = e0; p < e1; ++p) denom += expf(logit[eorder[p]] - m);
    float inv = (e1 > e0) ? (1.0f / denom) : 0.f;
    float acc = 0.f;
    for (int p = e0; p < e1; ++p) {
        int e = eorder[p];
        float a = expf(logit[e] - m) * inv;
        acc += a * hv[(size_t)srcArr[e] * 256 + t];
    }
    ctx[(size_t)v * 256 + t] = fmaxf(acc, 0.f);
}

// ---------------------------------------------------------------- fused GRU (6-tile GEMM + gates + relu)
__global__ __launch_bounds__(256) void gru_kernel(
    const float* __restrict__ ctx, const float* __restrict__ nf,
    const float* __restrict__ W_ih, const float* __restrict__ W_hh,
    const float* __restrict__ b_ih, const float* __restrict__ b_hh,
    float* __restrict__ hrelu, int V)
{
    __shared__ float As[2][16][68];
    __shared__ float Bs[6][16][68];
    int t = threadIdx.x;
    int tx = t & 15, ty = t >> 4;
    int n0 = blockIdx.x * 64, c0 = blockIdx.y * 64;
    float acc[6][4][4] = {};
    int ln = t >> 2;
    int kq = (t & 3) * 4;

    for (int k0 = 0; k0 < 256; k0 += 16) {
        int gn = n0 + ln;
        float4 a0 = make_float4(0.f, 0.f, 0.f, 0.f), a1 = a0;
        if (gn < V) {
            a0 = *(const float4*)(ctx + (size_t)gn * 256 + k0 + kq);
            a1 = *(const float4*)(nf + (size_t)gn * 256 + k0 + kq);
        }
        As[0][kq + 0][ln] = a0.x; As[0][kq + 1][ln] = a0.y;
        As[0][kq + 2][ln] = a0.z; As[0][kq + 3][ln] = a0.w;
        As[1][kq + 0][ln] = a1.x; As[1][kq + 1][ln] = a1.y;
        As[1][kq + 2][ln] = a1.z; As[1][kq + 3][ln] = a1.w;
        #pragma unroll
        for (int m = 0; m < 6; ++m) {
            const float* Wm = (m < 3) ? W_ih : W_hh;
            int coff = (m % 3) * 256;
            float4 wv = *(const float4*)(Wm + (size_t)(coff + c0 + ln) * 256 + k0 + kq);
            Bs[m][kq + 0][ln] = wv.x; Bs[m][kq + 1][ln] = wv.y;
            Bs[m][kq + 2][ln] = wv.z; Bs[m][kq + 3][ln] = wv.w;
        }
        __syncthreads();
        #pragma unroll
        for (int kk = 0; kk < 16; ++kk) {
            float aC[4], aN[4];
            *(float4*)aC = *(const float4*)&As[0][kk][tx * 4];
            *(float4*)aN = *(const float4*)&As[1][kk][tx * 4];
            #pragma unroll
            for (int m = 0; m < 6; ++m) {
                float b[4];
                *(float4*)b = *(const float4*)&Bs[m][kk][ty * 4];
                const float* a = (m < 3) ? aC : aN;
                #pragma unroll
                for (int i = 0; i < 4; ++i)
                    #pragma unroll
                    for (int j = 0; j < 4; ++j)
                        acc[m][i][j] += a[i] * b[j];
            }
        }
        __syncthreads();
    }
    float bihr[4], bihz[4], bihn[4], bhhr[4], bhhz[4], bhhn[4];
    *(float4*)bihr = *(const float4*)(b_ih + c0 + ty * 4);
    *(float4*)bihz = *(const float4*)(b_ih + 256 + c0 + ty * 4);
    *(float4*)bihn = *(const float4*)(b_ih + 512 + c0 + ty * 4);
    *(float4*)bhhr = *(const float4*)(b_hh + c0 + ty * 4);
    *(float4*)bhhz = *(const float4*)(b_hh + 256 + c0 + ty * 4);
    *(float4*)bhhn = *(const float4*)(b_hh + 512 + c0 + ty * 4);
    #pragma unroll
    for (int i = 0; i < 4; ++i) {
        int gn = n0 + tx * 4 + i;
        if (gn >= V) continue;
        float nfv[4], out[4];
        *(float4*)nfv = *(const float4*)(nf + (size_t)gn * 256 + c0 + ty * 4);
        #pragma unroll
        for (int j = 0; j < 4; ++j) {
            float r = sigmoidf(acc[0][i][j] + acc[3][i][j] + bihr[j] + bhhr[j]);
            float z = sigmoidf(acc[1][i][j] + acc[4][i][j] + bihz[j] + bhhz[j]);
            float nn = tanhf(acc[2][i][j] + bihn[j] + r * (acc[5][i][j] + bhhn[j]));
            float h = (1.f - z) * nn + z * nfv[j];
            out[j] = fmaxf(h, 0.f);
        }
        *(float4*)(hrelu + (size_t)gn * 256 + c0 + ty * 4) = make_float4(out[0], out[1], out[2], out[3]);
    }
}

// ---------------------------------------------------------------- row LayerNorm over 256 (optional trailing relu)
__global__ __launch_bounds__(256) void ln_kernel(
    const float* __restrict__ in, float* __restrict__ out,
    const float* __restrict__ g, const float* __restrict__ b, int relu_after)
{
    __shared__ float red[8];
    int v = blockIdx.x, t = threadIdx.x;
    float x = in[(size_t)v * 256 + t];
    float s1 = x, s2 = x * x;
    blockSum2(s1, s2, red);
    float mu = s1 * (1.0f / 256.0f);
    float var = s2 * (1.0f / 256.0f) - mu * mu;
    float y = (x - mu) * rsqrtf(var + 1e-5f) * g[t] + b[t];
    if (relu_after) y = fmaxf(y, 0.f);
    out[(size_t)v * 256 + t] = y;
}

// ---------------------------------------------------------------- launcher
extern "C" void kernel_launch(void* const* d_in, const int* in_sizes, int n_in,
                              void* d_out, int out_size, void* d_ws, size_t ws_size,
                              hipStream_t stream)
{
    const float* nf    = (const float*)d_in[0];
    const int*   src   = (const int*)d_in[1];
    const int*   dst   = (const int*)d_in[2];
    const float* Wp    = (const float*)d_in[3];
    const float* bp    = (const float*)d_in[4];
    const float* gp    = (const float*)d_in[5];
    const float* betap = (const float*)d_in[6];
    const float* Wk    = (const float*)d_in[7];
    const float* bk    = (const float*)d_in[8];
    const float* gk    = (const float*)d_in[9];
    const float* betak = (const float*)d_in[10];
    const float* We    = (const float*)d_in[11];
    const float* be    = (const float*)d_in[12];
    const float* Wn    = (const float*)d_in[13];
    const float* bn    = (const float*)d_in[14];
    const float* W_ih  = (const float*)d_in[15];
    const float* W_hh  = (const float*)d_in[16];
    const float* b_ih  = (const float*)d_in[17];
    const float* b_hh  = (const float*)d_in[18];
    const float* g_ln  = (const float*)d_in[19];
    const float* bt_ln = (const float*)d_in[20];
    const float* Wc    = (const float*)d_in[21];
    const float* bc    = (const float*)d_in[22];
    const float* gc    = (const float*)d_in[23];
    const float* betac = (const float*)d_in[24];

    int V = in_sizes[0] / 256;
    int E = in_sizes[1];

    char* w = (char*)d_ws;
    auto alloc = [&](size_t bytes) -> char* {
        char* p = w;
        w += (bytes + 255) & ~(size_t)255;
        return p;
    };
    float* npj    = (float*)alloc((size_t)V * 20 * 4);
    float* kron   = (float*)alloc((size_t)V * 256 * 4);
    float* hv     = (float*)alloc((size_t)V * 256 * 4);   // also h_relu / gru_out
    float* ctxb   = (float*)alloc((size_t)V * 256 * 4);   // also pre-LN final
    float* logit  = (float*)alloc((size_t)E * 4);
    int*   deg    = (int*)alloc((size_t)V * 4);
    int*   cnt    = (int*)alloc((size_t)V * 4);
    int*   rowp   = (int*)alloc((size_t)(V + 1) * 4);
    int*   eorder = (int*)alloc((size_t)E * 4);

    hipMemsetAsync(deg, 0, (size_t)V * 4, stream);
    hipMemsetAsync(cnt, 0, (size_t)V * 4, stream);

    npj_kernel<<<V, 64, 0, stream>>>(nf, Wp, bp, gp, betap, npj, V);
    deg_kernel<<<(E + 255) / 256, 256, 0, stream>>>(dst, deg, E);
    scan_kernel<<<1, 1024, 0, stream>>>(deg, rowp, V);
    scatter_kernel<<<(E + 255) / 256, 256, 0, stream>>>(dst, rowp, cnt, eorder, E);
    logit_kernel<<<(E + 3) / 4, 256, 0, stream>>>(nf, src, dst, We, be, logit, E);
    gemm64_kernel<<<dim3((V + 63) / 64, 4), 256, 0, stream>>>(nf, nf, 256, 256, Wn, bn, hv, V);
    kron_kernel<<<(V + KG - 1) / KG, 256, 0, stream>>>(npj, src, eorder, rowp, Wk, bk, gk, betak, kron, V);
    ctx_kernel<<<V, 256, 0, stream>>>(hv, logit, src, eorder, rowp, ctxb, V);
    gru_kernel<<<dim3((V + 63) / 64, 4), 256, 0, stream>>>(ctxb, nf, W_ih, W_hh, b_ih, b_hh, hv, V);
    ln_kernel<<<V, 256, 0, stream>>>(hv, hv, g_ln, bt_ln, 0);
    gemm64_kernel<<<dim3((V + 63) / 64, 4), 256, 0, stream>>>(hv, kron, 256, 512, Wc, bc, ctxb, V);
    ln_kernel<<<V, 256, 0, stream>>>(ctxb, (float*)d_out, gc, betac, 1);
}

// Round 2
// 2700.333 us; speedup vs baseline: 1.2864x; 1.2864x over previous
//
#include <hip/hip_runtime.h>
#include <hip/hip_bf16.h>
#include <math.h>

#define KG 4   // dst nodes per block in kron kernel (one per wave)

// ---------------------------------------------------------------- helpers
__device__ __forceinline__ void blockSum2(float& s1, float& s2, float* red) {
    #pragma unroll
    for (int off = 32; off > 0; off >>= 1) {
        s1 += __shfl_xor(s1, off);
        s2 += __shfl_xor(s2, off);
    }
    int lane = threadIdx.x & 63, wid = threadIdx.x >> 6;
    if (lane == 0) { red[wid] = s1; red[4 + wid] = s2; }
    __syncthreads();
    s1 = red[0] + red[1] + red[2] + red[3];
    s2 = red[4] + red[5] + red[6] + red[7];
}

__device__ __forceinline__ float sigmoidf(float x) { return 1.0f / (1.0f + expf(-x)); }

// ---------------------------------------------------------------- npj = relu(LN(nf@Wp + bp))
__global__ __launch_bounds__(64) void npj_kernel(
    const float* __restrict__ nf, const float* __restrict__ Wp,
    const float* __restrict__ bp, const float* __restrict__ gp,
    const float* __restrict__ betap, float* __restrict__ npj, int V)
{
    int v = blockIdx.x;
    int j = threadIdx.x;
    float acc = 0.f;
    if (j < 20) {
        acc = bp[j];
        const float* row = nf + (size_t)v * 256;
        #pragma unroll 8
        for (int i = 0; i < 256; ++i) acc += row[i] * Wp[i * 20 + j];
    }
    float x = (j < 20) ? acc : 0.f;
    float s1 = x, s2 = x * x;
    #pragma unroll
    for (int off = 32; off > 0; off >>= 1) {
        s1 += __shfl_xor(s1, off);
        s2 += __shfl_xor(s2, off);
    }
    float mu = s1 * (1.0f / 20.0f);
    float var = s2 * (1.0f / 20.0f) - mu * mu;
    if (j < 20) {
        float y = (acc - mu) * rsqrtf(var + 1e-5f) * gp[j] + betap[j];
        npj[(size_t)v * 20 + j] = fmaxf(y, 0.f);
    }
}

// ---------------------------------------------------------------- CSR build
__global__ __launch_bounds__(256) void deg_kernel(const int* __restrict__ dst, int* __restrict__ deg, int E) {
    int e = blockIdx.x * 256 + threadIdx.x;
    if (e < E) atomicAdd(&deg[dst[e]], 1);
}

// single-block scan, shuffle-based (3 barriers per 1024-tile)
__global__ __launch_bounds__(1024) void scan_kernel(const int* __restrict__ deg, int* __restrict__ row, int V) {
    __shared__ int wsum[16];
    __shared__ int carry_sh;
    int t = threadIdx.x, lane = t & 63, wid = t >> 6;
    if (t == 0) carry_sh = 0;
    __syncthreads();
    for (int base = 0; base < V; base += 1024) {
        int i = base + t;
        int val = (i < V) ? deg[i] : 0;
        #pragma unroll
        for (int s = 1; s < 64; s <<= 1) {
            int n = __shfl_up(val, s);
            if (lane >= s) val += n;
        }
        if (lane == 63) wsum[wid] = val;
        __syncthreads();
        if (wid == 0) {
            int x = (lane < 16) ? wsum[lane] : 0;
            #pragma unroll
            for (int s = 1; s < 16; s <<= 1) {
                int n = __shfl_up(x, s);
                if (lane >= s) x += n;
            }
            if (lane < 16) wsum[lane] = x;
        }
        __syncthreads();
        int wprefix = (wid > 0) ? wsum[wid - 1] : 0;
        int c = carry_sh;
        int incl = c + wprefix + val;
        if (i < V) row[i + 1] = incl;
        __syncthreads();
        if (t == 1023) carry_sh = incl;
        // next tile's first __syncthreads orders this write before reads
    }
    if (t == 0) row[0] = 0;
}

__global__ __launch_bounds__(256) void scatter_kernel(
    const int* __restrict__ dst, const int* __restrict__ row,
    int* __restrict__ cnt, int* __restrict__ eorder, int E)
{
    int e = blockIdx.x * 256 + threadIdx.x;
    if (e < E) {
        int d = dst[e];
        int pos = row[d] + atomicAdd(&cnt[d], 1);
        eorder[pos] = e;
    }
}

// ---------------------------------------------------------------- edge logits = relu([nf[dst],nf[src]]@We + be)
__global__ __launch_bounds__(256) void logit_kernel(
    const float* __restrict__ nf, const int* __restrict__ src, const int* __restrict__ dst,
    const float* __restrict__ We, const float* __restrict__ be,
    float* __restrict__ logit, int E)
{
    int wid = threadIdx.x >> 6, lane = threadIdx.x & 63;
    int e = blockIdx.x * 4 + wid;
    if (e >= E) return;
    int d = dst[e], s = src[e];
    const float* row = (lane < 32) ? (nf + (size_t)d * 256) : (nf + (size_t)s * 256 - 256);
    int i = lane * 8;
    float4 x0 = *(const float4*)(row + i);
    float4 x1 = *(const float4*)(row + i + 4);
    float4 w0 = *(const float4*)(We + i);
    float4 w1 = *(const float4*)(We + i + 4);
    float sum = x0.x * w0.x + x0.y * w0.y + x0.z * w0.z + x0.w * w0.w
              + x1.x * w1.x + x1.y * w1.y + x1.z * w1.z + x1.w * w1.w;
    #pragma unroll
    for (int off = 32; off > 0; off >>= 1) sum += __shfl_xor(sum, off);
    if (lane == 0) logit[e] = fmaxf(sum + be[0], 0.f);
}

// ---------------------------------------------------------------- kron branch (CSR-grouped by dst)
// Stage 1 (block-cooperative, 2 barriers): T_g[a][o] = sum_k npj[v0+g][k]*Wk[a*20+k][o] -> LDS bf16.
// Stage 2 (wave-private, barrier-free): wave g owns dst v0+g; lane owns 4 channels;
// T fragment in registers; per edge: shfl-broadcast npj[src], 80 FMA, wave-butterfly LN, reg accumulate.
__global__ __launch_bounds__(256) void kron_kernel(
    const float* __restrict__ npj, const int* __restrict__ srcArr,
    const int* __restrict__ eorder, const int* __restrict__ rowPtr,
    const float* __restrict__ Wk, const float* __restrict__ bk,
    const float* __restrict__ gkv, const float* __restrict__ betak,
    float* __restrict__ kron_feat, int V)
{
    __shared__ __hip_bfloat16 T[KG * 20 * 256];   // 40 KB, [g][a][c]
    __shared__ float dsh[KG * 20];
    int t = threadIdx.x;
    int v0 = blockIdx.x * KG;

    if (t < KG * 20) {
        int g = t / 20, k = t % 20;
        int v = v0 + g;
        dsh[t] = (v < V) ? npj[(size_t)v * 20 + k] : 0.f;
    }
    __syncthreads();

    float dreg[KG][20];
    #pragma unroll
    for (int g = 0; g < KG; ++g)
        #pragma unroll
        for (int k = 0; k < 20; ++k) dreg[g][k] = dsh[g * 20 + k];

    for (int a = 0; a < 20; ++a) {
        float w[20];
        #pragma unroll
        for (int k = 0; k < 20; ++k) w[k] = Wk[(size_t)(a * 20 + k) * 256 + t];
        #pragma unroll
        for (int g = 0; g < KG; ++g) {
            float s = 0.f;
            #pragma unroll
            for (int k = 0; k < 20; ++k) s += dreg[g][k] * w[k];
            T[(g * 20 + a) * 256 + t] = __float2bfloat16(s);
        }
    }
    __syncthreads();

    // ---- stage 2: wave-private ----
    int wid = t >> 6, lane = t & 63;
    int v = v0 + wid;
    if (v >= V) return;
    int c0 = lane * 4;

    float Tr[20][4];
    #pragma unroll
    for (int a = 0; a < 20; ++a) {
        const __hip_bfloat16* tp = &T[(wid * 20 + a) * 256 + c0];
        Tr[a][0] = __bfloat162float(tp[0]);
        Tr[a][1] = __bfloat162float(tp[1]);
        Tr[a][2] = __bfloat162float(tp[2]);
        Tr[a][3] = __bfloat162float(tp[3]);
    }
    float4 bkv = *(const float4*)(bk + c0);
    float4 gk4 = *(const float4*)(gkv + c0);
    float4 bt4 = *(const float4*)(betak + c0);

    float acc0 = 0.f, acc1 = 0.f, acc2 = 0.f, acc3 = 0.f;
    int e0 = rowPtr[v], e1 = rowPtr[v + 1];
    for (int p = e0; p < e1; ++p) {
        int e = eorder[p];
        int sv = srcArr[e];
        float sval = (lane < 20) ? npj[(size_t)sv * 20 + lane] : 0.f;
        float y0 = bkv.x, y1 = bkv.y, y2 = bkv.z, y3 = bkv.w;
        #pragma unroll
        for (int a = 0; a < 20; ++a) {
            float s_a = __shfl(sval, a);
            y0 += s_a * Tr[a][0];
            y1 += s_a * Tr[a][1];
            y2 += s_a * Tr[a][2];
            y3 += s_a * Tr[a][3];
        }
        float s1 = y0 + y1 + y2 + y3;
        float s2 = y0 * y0 + y1 * y1 + y2 * y2 + y3 * y3;
        #pragma unroll
        for (int off = 32; off > 0; off >>= 1) {
            s1 += __shfl_xor(s1, off);
            s2 += __shfl_xor(s2, off);
        }
        float mu = s1 * (1.0f / 256.0f);
        float var = s2 * (1.0f / 256.0f) - mu * mu;
        float rs = rsqrtf(var + 1e-5f);
        acc0 += fmaxf((y0 - mu) * rs * gk4.x + bt4.x, 0.f);
        acc1 += fmaxf((y1 - mu) * rs * gk4.y + bt4.y, 0.f);
        acc2 += fmaxf((y2 - mu) * rs * gk4.z + bt4.z, 0.f);
        acc3 += fmaxf((y3 - mu) * rs * gk4.w + bt4.w, 0.f);
    }
    *(float4*)(kron_feat + (size_t)v * 256 + c0) = make_float4(acc0, acc1, acc2, acc3);
}

// ---------------------------------------------------------------- generic 64x64 tiled GEMM
__global__ __launch_bounds__(256) void gemm64_kernel(
    const float* __restrict__ A1, const float* __restrict__ A2, int ksplit, int K,
    const float* __restrict__ B, const float* __restrict__ bias,
    float* __restrict__ C, int M)
{
    __shared__ float As[16][68];
    __shared__ float Bs[16][68];
    int t = threadIdx.x;
    int tx = t & 15, ty = t >> 4;
    int n0 = blockIdx.x * 64, c0 = blockIdx.y * 64;
    float acc[4][4] = {};
    int lnode = t >> 2;
    int lkq = (t & 3) * 4;
    int lkr = t >> 4;
    int lc = (t & 15) * 4;

    for (int k0 = 0; k0 < K; k0 += 16) {
        int gn = n0 + lnode;
        float4 av = make_float4(0.f, 0.f, 0.f, 0.f);
        if (gn < M) {
            int kk = k0 + lkq;
            const float* srcp = (kk < ksplit) ? (A1 + (size_t)gn * 256 + kk)
                                              : (A2 + (size_t)gn * 256 + (kk - ksplit));
            av = *(const float4*)srcp;
        }
        As[lkq + 0][lnode] = av.x; As[lkq + 1][lnode] = av.y;
        As[lkq + 2][lnode] = av.z; As[lkq + 3][lnode] = av.w;
        float4 bv = *(const float4*)(B + (size_t)(k0 + lkr) * 256 + c0 + lc);
        *(float4*)&Bs[lkr][lc] = bv;
        __syncthreads();
        #pragma unroll
        for (int kk = 0; kk < 16; ++kk) {
            float a[4], b[4];
            *(float4*)a = *(const float4*)&As[kk][tx * 4];
            *(float4*)b = *(const float4*)&Bs[kk][ty * 4];
            #pragma unroll
            for (int i = 0; i < 4; ++i)
                #pragma unroll
                for (int j = 0; j < 4; ++j)
                    acc[i][j] += a[i] * b[j];
        }
        __syncthreads();
    }
    float bvals[4];
    *(float4*)bvals = *(const float4*)(bias + c0 + ty * 4);
    #pragma unroll
    for (int i = 0; i < 4; ++i) {
        int gn = n0 + tx * 4 + i;
        if (gn < M) {
            float4 o = make_float4(acc[i][0] + bvals[0], acc[i][1] + bvals[1],
                                   acc[i][2] + bvals[2], acc[i][3] + bvals[3]);
            *(float4*)(C + (size_t)gn * 256 + c0 + ty * 4) = o;
        }
    }
}

// ---------------------------------------------------------------- attention stats (max, 1/denom) per dst
__global__ __launch_bounds__(256) void att_kernel(
    const float* __restrict__ logit, const int* __restrict__ eorder,
    const int* __restrict__ rowPtr, float* __restrict__ mArr, float* __restrict__ invArr, int V)
{
    int wid = threadIdx.x >> 6, lane = threadIdx.x & 63;
    int v = blockIdx.x * 4 + wid;
    if (v >= V) return;
    int e0 = rowPtr[v], e1 = rowPtr[v + 1];
    float m = -1e30f;
    for (int p = e0 + lane; p < e1; p += 64) m = fmaxf(m, logit[eorder[p]]);
    #pragma unroll
    for (int off = 32; off > 0; off >>= 1) m = fmaxf(m, __shfl_xor(m, off));
    float d = 0.f;
    for (int p = e0 + lane; p < e1; p += 64) d += expf(logit[eorder[p]] - m);
    #pragma unroll
    for (int off = 32; off > 0; off >>= 1) d += __shfl_xor(d, off);
    if (lane == 0) {
        mArr[v] = m;
        invArr[v] = (e1 > e0) ? (1.0f / d) : 0.f;
    }
}

// ---------------------------------------------------------------- weighted context aggregation (single pass)
__global__ __launch_bounds__(256) void ctx_kernel(
    const float* __restrict__ hv, const float* __restrict__ logit,
    const float* __restrict__ mArr, const float* __restrict__ invArr,
    const int* __restrict__ srcArr, const int* __restrict__ eorder,
    const int* __restrict__ rowPtr, float* __restrict__ ctx, int V)
{
    int v = blockIdx.x;
    int t = threadIdx.x;
    int e0 = rowPtr[v], e1 = rowPtr[v + 1];
    float m = mArr[v], inv = invArr[v];
    float acc = 0.f;
    for (int p = e0; p < e1; ++p) {
        int e = eorder[p];
        float a = expf(logit[e] - m) * inv;
        acc += a * hv[(size_t)srcArr[e] * 256 + t];
    }
    ctx[(size_t)v * 256 + t] = fmaxf(acc, 0.f);
}

// ---------------------------------------------------------------- fused GRU (6-tile GEMM + gates + relu)
__global__ __launch_bounds__(256) void gru_kernel(
    const float* __restrict__ ctx, const float* __restrict__ nf,
    const float* __restrict__ W_ih, const float* __restrict__ W_hh,
    const float* __restrict__ b_ih, const float* __restrict__ b_hh,
    float* __restrict__ hrelu, int V)
{
    __shared__ float As[2][16][68];
    __shared__ float Bs[6][16][68];
    int t = threadIdx.x;
    int tx = t & 15, ty = t >> 4;
    int n0 = blockIdx.x * 64, c0 = blockIdx.y * 64;
    float acc[6][4][4] = {};
    int ln = t >> 2;
    int kq = (t & 3) * 4;

    for (int k0 = 0; k0 < 256; k0 += 16) {
        int gn = n0 + ln;
        float4 a0 = make_float4(0.f, 0.f, 0.f, 0.f), a1 = a0;
        if (gn < V) {
            a0 = *(const float4*)(ctx + (size_t)gn * 256 + k0 + kq);
            a1 = *(const float4*)(nf + (size_t)gn * 256 + k0 + kq);
        }
        As[0][kq + 0][ln] = a0.x; As[0][kq + 1][ln] = a0.y;
        As[0][kq + 2][ln] = a0.z; As[0][kq + 3][ln] = a0.w;
        As[1][kq + 0][ln] = a1.x; As[1][kq + 1][ln] = a1.y;
        As[1][kq + 2][ln] = a1.z; As[1][kq + 3][ln] = a1.w;
        #pragma unroll
        for (int m = 0; m < 6; ++m) {
            const float* Wm = (m < 3) ? W_ih : W_hh;
            int coff = (m % 3) * 256;
            float4 wv = *(const float4*)(Wm + (size_t)(coff + c0 + ln) * 256 + k0 + kq);
            Bs[m][kq + 0][ln] = wv.x; Bs[m][kq + 1][ln] = wv.y;
            Bs[m][kq + 2][ln] = wv.z; Bs[m][kq + 3][ln] = wv.w;
        }
        __syncthreads();
        #pragma unroll
        for (int kk = 0; kk < 16; ++kk) {
            float aC[4], aN[4];
            *(float4*)aC = *(const float4*)&As[0][kk][tx * 4];
            *(float4*)aN = *(const float4*)&As[1][kk][tx * 4];
            #pragma unroll
            for (int m = 0; m < 6; ++m) {
                float b[4];
                *(float4*)b = *(const float4*)&Bs[m][kk][ty * 4];
                const float* a = (m < 3) ? aC : aN;
                #pragma unroll
                for (int i = 0; i < 4; ++i)
                    #pragma unroll
                    for (int j = 0; j < 4; ++j)
                        acc[m][i][j] += a[i] * b[j];
            }
        }
        __syncthreads();
    }
    float bihr[4], bihz[4], bihn[4], bhhr[4], bhhz[4], bhhn[4];
    *(float4*)bihr = *(const float4*)(b_ih + c0 + ty * 4);
    *(float4*)bihz = *(const float4*)(b_ih + 256 + c0 + ty * 4);
    *(float4*)bihn = *(const float4*)(b_ih + 512 + c0 + ty * 4);
    *(float4*)bhhr = *(const float4*)(b_hh + c0 + ty * 4);
    *(float4*)bhhz = *(const float4*)(b_hh + 256 + c0 + ty * 4);
    *(float4*)bhhn = *(const float4*)(b_hh + 512 + c0 + ty * 4);
    #pragma unroll
    for (int i = 0; i < 4; ++i) {
        int gn = n0 + tx * 4 + i;
        if (gn >= V) continue;
        float nfv[4], out[4];
        *(float4*)nfv = *(const float4*)(nf + (size_t)gn * 256 + c0 + ty * 4);
        #pragma unroll
        for (int j = 0; j < 4; ++j) {
            float r = sigmoidf(acc[0][i][j] + acc[3][i][j] + bihr[j] + bhhr[j]);
            float z = sigmoidf(acc[1][i][j] + acc[4][i][j] + bihz[j] + bhhz[j]);
            float nn = tanhf(acc[2][i][j] + bihn[j] + r * (acc[5][i][j] + bhhn[j]));
            float h = (1.f - z) * nn + z * nfv[j];
            out[j] = fmaxf(h, 0.f);
        }
        *(float4*)(hrelu + (size_t)gn * 256 + c0 + ty * 4) = make_float4(out[0], out[1], out[2], out[3]);
    }
}

// ---------------------------------------------------------------- row LayerNorm over 256 (optional trailing relu)
__global__ __launch_bounds__(256) void ln_kernel(
    const float* __restrict__ in, float* __restrict__ out,
    const float* __restrict__ g, const float* __restrict__ b, int relu_after)
{
    __shared__ float red[8];
    int v = blockIdx.x, t = threadIdx.x;
    float x = in[(size_t)v * 256 + t];
    float s1 = x, s2 = x * x;
    blockSum2(s1, s2, red);
    float mu = s1 * (1.0f / 256.0f);
    float var = s2 * (1.0f / 256.0f) - mu * mu;
    float y = (x - mu) * rsqrtf(var + 1e-5f) * g[t] + b[t];
    if (relu_after) y = fmaxf(y, 0.f);
    out[(size_t)v * 256 + t] = y;
}

// ---------------------------------------------------------------- launcher
extern "C" void kernel_launch(void* const* d_in, const int* in_sizes, int n_in,
                              void* d_out, int out_size, void* d_ws, size_t ws_size,
                              hipStream_t stream)
{
    const float* nf    = (const float*)d_in[0];
    const int*   src   = (const int*)d_in[1];
    const int*   dst   = (const int*)d_in[2];
    const float* Wp    = (const float*)d_in[3];
    const float* bp    = (const float*)d_in[4];
    const float* gp    = (const float*)d_in[5];
    const float* betap = (const float*)d_in[6];
    const float* Wk    = (const float*)d_in[7];
    const float* bk    = (const float*)d_in[8];
    const float* gk    = (const float*)d_in[9];
    const float* betak = (const float*)d_in[10];
    const float* We    = (const float*)d_in[11];
    const float* be    = (const float*)d_in[12];
    const float* Wn    = (const float*)d_in[13];
    const float* bn    = (const float*)d_in[14];
    const float* W_ih  = (const float*)d_in[15];
    const float* W_hh  = (const float*)d_in[16];
    const float* b_ih  = (const float*)d_in[17];
    const float* b_hh  = (const float*)d_in[18];
    const float* g_ln  = (const float*)d_in[19];
    const float* bt_ln = (const float*)d_in[20];
    const float* Wc    = (const float*)d_in[21];
    const float* bc    = (const float*)d_in[22];
    const float* gc    = (const float*)d_in[23];
    const float* betac = (const float*)d_in[24];

    int V = in_sizes[0] / 256;
    int E = in_sizes[1];

    char* w = (char*)d_ws;
    auto alloc = [&](size_t bytes) -> char* {
        char* p = w;
        w += (bytes + 255) & ~(size_t)255;
        return p;
    };
    float* npj    = (float*)alloc((size_t)V * 20 * 4);
    float* kron   = (float*)alloc((size_t)V * 256 * 4);
    float* hv     = (float*)alloc((size_t)V * 256 * 4);   // also h_relu / gru_out
    float* ctxb   = (float*)alloc((size_t)V * 256 * 4);   // also pre-LN final
    float* logit  = (float*)alloc((size_t)E * 4);
    float* mArr   = (float*)alloc((size_t)V * 4);
    float* invArr = (float*)alloc((size_t)V * 4);
    int*   deg    = (int*)alloc((size_t)V * 4);
    int*   cnt    = (int*)alloc((size_t)V * 4);
    int*   rowp   = (int*)alloc((size_t)(V + 1) * 4);
    int*   eorder = (int*)alloc((size_t)E * 4);

    hipMemsetAsync(deg, 0, (size_t)V * 4, stream);
    hipMemsetAsync(cnt, 0, (size_t)V * 4, stream);

    npj_kernel<<<V, 64, 0, stream>>>(nf, Wp, bp, gp, betap, npj, V);
    deg_kernel<<<(E + 255) / 256, 256, 0, stream>>>(dst, deg, E);
    scan_kernel<<<1, 1024, 0, stream>>>(deg, rowp, V);
    scatter_kernel<<<(E + 255) / 256, 256, 0, stream>>>(dst, rowp, cnt, eorder, E);
    logit_kernel<<<(E + 3) / 4, 256, 0, stream>>>(nf, src, dst, We, be, logit, E);
    gemm64_kernel<<<dim3((V + 63) / 64, 4), 256, 0, stream>>>(nf, nf, 256, 256, Wn, bn, hv, V);
    kron_kernel<<<(V + KG - 1) / KG, 256, 0, stream>>>(npj, src, eorder, rowp, Wk, bk, gk, betak, kron, V);
    att_kernel<<<(V + 3) / 4, 256, 0, stream>>>(logit, eorder, rowp, mArr, invArr, V);
    ctx_kernel<<<V, 256, 0, stream>>>(hv, logit, mArr, invArr, src, eorder, rowp, ctxb, V);
    gru_kernel<<<dim3((V + 63) / 64, 4), 256, 0, stream>>>(ctxb, nf, W_ih, W_hh, b_ih, b_hh, hv, V);
    ln_kernel<<<V, 256, 0, stream>>>(hv, hv, g_ln, bt_ln, 0);
    gemm64_kernel<<<dim3((V + 63) / 64, 4), 256, 0, stream>>>(hv, kron, 256, 512, Wc, bc, ctxb, V);
    ln_kernel<<<V, 256, 0, stream>>>(ctxb, (float*)d_out, gc, betac, 1);
}

// Round 3
// 1863.565 us; speedup vs baseline: 1.8640x; 1.4490x over previous
//
#include <hip/hip_runtime.h>
#include <hip/hip_bf16.h>
#include <math.h>

#define KG 4   // dst nodes per block in kron kernel (one per wave)

typedef __attribute__((ext_vector_type(8))) short bfrag;   // 8 bf16 (4 VGPRs)
typedef __attribute__((ext_vector_type(4))) float cfrag;   // 4 fp32 acc

__device__ __forceinline__ ushort f2bf(float f) {
    __hip_bfloat16 h = __float2bfloat16(f);
    return *(ushort*)&h;
}
__device__ __forceinline__ float bf2f(ushort u) {
    __hip_bfloat16 h;
    *(ushort*)&h = u;
    return __bfloat162float(h);
}

// ---------------------------------------------------------------- helpers
__device__ __forceinline__ void blockSum2(float& s1, float& s2, float* red) {
    #pragma unroll
    for (int off = 32; off > 0; off >>= 1) {
        s1 += __shfl_xor(s1, off);
        s2 += __shfl_xor(s2, off);
    }
    int lane = threadIdx.x & 63, wid = threadIdx.x >> 6;
    if (lane == 0) { red[wid] = s1; red[4 + wid] = s2; }
    __syncthreads();
    s1 = red[0] + red[1] + red[2] + red[3];
    s2 = red[4] + red[5] + red[6] + red[7];
}

__device__ __forceinline__ float sigmoidf(float x) { return 1.0f / (1.0f + expf(-x)); }

// ---------------------------------------------------------------- bf16 cast (4 elems/thread)
__global__ __launch_bounds__(256) void cast_bf16_kernel(
    const float* __restrict__ x, ushort* __restrict__ y, int n)
{
    int i = (blockIdx.x * 256 + threadIdx.x) * 4;
    if (i < n) {
        float4 v = *(const float4*)(x + i);
        ushort4 o;
        o.x = f2bf(v.x); o.y = f2bf(v.y); o.z = f2bf(v.z); o.w = f2bf(v.w);
        *(ushort4*)(y + i) = o;
    }
}

// ---------------------------------------------------------------- weight prep: bf16 B^T layouts
// BTrz[n][k] (512x512): k<256 -> W_ih[n][k], else W_hh[n][k-256]   (r,z gate rows 0..511)
// BTin[n][k] (256x256): W_ih[512+n][k] ;  BThn: W_hh[512+n][k]
// BTn [n][k] (256x256): Wn[k][n] (transpose); BTc[n][k] (256x512): Wc[k][n]
// bias_rz[n] = b_ih[n] + b_hh[n]  (n<512)
__global__ __launch_bounds__(256) void prep_w_kernel(
    const float* __restrict__ Wn, const float* __restrict__ Wih,
    const float* __restrict__ Whh, const float* __restrict__ Wc,
    const float* __restrict__ b_ih, const float* __restrict__ b_hh,
    ushort* __restrict__ BTn, ushort* __restrict__ BTrz,
    ushort* __restrict__ BTin, ushort* __restrict__ BThn,
    ushort* __restrict__ BTc, float* __restrict__ bias_rz)
{
    int id = blockIdx.x * 256 + threadIdx.x;
    if (id < 262144) {
        int n = id >> 9, k = id & 511;
        float v = (k < 256) ? Wih[n * 256 + k] : Whh[n * 256 + k - 256];
        BTrz[id] = f2bf(v);
    } else if (id < 327680) {
        int j = id - 262144; int n = j >> 8, k = j & 255;
        BTin[j] = f2bf(Wih[(512 + n) * 256 + k]);
    } else if (id < 393216) {
        int j = id - 327680; int n = j >> 8, k = j & 255;
        BThn[j] = f2bf(Whh[(512 + n) * 256 + k]);
    } else if (id < 458752) {
        int j = id - 393216; int n = j >> 8, k = j & 255;
        BTn[j] = f2bf(Wn[k * 256 + n]);
    } else if (id < 589824) {
        int j = id - 458752; int n = j >> 9, k = j & 511;
        BTc[j] = f2bf(Wc[k * 256 + n]);
    } else if (id < 590336) {
        int n = id - 589824;
        bias_rz[n] = b_ih[n] + b_hh[n];
    }
}

// ---------------------------------------------------------------- generic bf16 MFMA GEMM
// C[M,N] = [A1|A2][M,K] @ B^T'[N,K] + bias ; A row-major bf16 (lda), split at ksplit.
// 128x128 block tile, 4 waves in 2x2, each wave 64x64 via 4x4 of 16x16x32 MFMA. BK=64.
// LDS XOR-swizzle: chunk (row,kc) at row*64 + (kc^(row&7))*8 shorts.
__global__ __launch_bounds__(256) void mfma_gemm_kernel(
    const ushort* __restrict__ A1, const ushort* __restrict__ A2, int ksplit, int lda,
    const ushort* __restrict__ B, const float* __restrict__ bias,
    void* __restrict__ Cout, int store_bf16,
    int M, int N, int K, int ldc)
{
    __shared__ ushort As[128 * 64];
    __shared__ ushort Bs[128 * 64];
    int t = threadIdx.x;
    int m0 = blockIdx.x * 128, n0 = blockIdx.y * 128;
    int w = t >> 6, lane = t & 63;
    int q = lane >> 4, r = lane & 15;
    int wm = (w & 1) * 64, wn = (w >> 1) * 64;

    cfrag acc[4][4] = {};

    int srow_base = t >> 3;   // 0..31
    int skc = t & 7;

    for (int k0 = 0; k0 < K; k0 += 64) {
        const ushort* Ap; int kb;
        if (k0 < ksplit) { Ap = A1; kb = k0; } else { Ap = A2; kb = k0 - ksplit; }
        int4 av[4], bv[4];
        #pragma unroll
        for (int i = 0; i < 4; ++i) {
            int row = i * 32 + srow_base;
            int grow = m0 + row;
            av[i] = make_int4(0, 0, 0, 0);
            if (grow < M) av[i] = *(const int4*)(Ap + (size_t)grow * lda + kb + skc * 8);
            bv[i] = *(const int4*)(B + (size_t)(n0 + row) * K + k0 + skc * 8);
        }
        __syncthreads();
        #pragma unroll
        for (int i = 0; i < 4; ++i) {
            int row = i * 32 + srow_base;
            int off = row * 64 + ((skc ^ (row & 7)) * 8);
            *(int4*)&As[off] = av[i];
            *(int4*)&Bs[off] = bv[i];
        }
        __syncthreads();
        #pragma unroll
        for (int s = 0; s < 2; ++s) {
            bfrag af[4], bfr[4];
            int kc = s * 4 + q;
            #pragma unroll
            for (int mi = 0; mi < 4; ++mi) {
                int arow = wm + mi * 16 + r;
                af[mi] = *(const bfrag*)&As[arow * 64 + ((kc ^ (arow & 7)) * 8)];
            }
            #pragma unroll
            for (int ni = 0; ni < 4; ++ni) {
                int brow = wn + ni * 16 + r;
                bfr[ni] = *(const bfrag*)&Bs[brow * 64 + ((kc ^ (brow & 7)) * 8)];
            }
            #pragma unroll
            for (int mi = 0; mi < 4; ++mi)
                #pragma unroll
                for (int ni = 0; ni < 4; ++ni)
                    acc[mi][ni] = __builtin_amdgcn_mfma_f32_16x16x32_bf16(
                        af[mi], bfr[ni], acc[mi][ni], 0, 0, 0);
        }
    }

    // epilogue: C/D layout col=lane&15, row=(lane>>4)*4+reg
    float bvld[4];
    #pragma unroll
    for (int ni = 0; ni < 4; ++ni) bvld[ni] = bias[n0 + wn + ni * 16 + r];
    #pragma unroll
    for (int mi = 0; mi < 4; ++mi) {
        #pragma unroll
        for (int v = 0; v < 4; ++v) {
            int grow = m0 + wm + mi * 16 + q * 4 + v;
            if (grow >= M) continue;
            #pragma unroll
            for (int ni = 0; ni < 4; ++ni) {
                int gcol = n0 + wn + ni * 16 + r;
                float val = acc[mi][ni][v] + bvld[ni];
                if (store_bf16) ((ushort*)Cout)[(size_t)grow * ldc + gcol] = f2bf(val);
                else            ((float*)Cout)[(size_t)grow * ldc + gcol] = val;
            }
        }
    }
}

// ---------------------------------------------------------------- npj = relu(LN(nf@Wp + bp))
__global__ __launch_bounds__(64) void npj_kernel(
    const float* __restrict__ nf, const float* __restrict__ Wp,
    const float* __restrict__ bp, const float* __restrict__ gp,
    const float* __restrict__ betap, float* __restrict__ npj, int V)
{
    int v = blockIdx.x;
    int j = threadIdx.x;
    float acc = 0.f;
    if (j < 20) {
        acc = bp[j];
        const float* row = nf + (size_t)v * 256;
        #pragma unroll 8
        for (int i = 0; i < 256; ++i) acc += row[i] * Wp[i * 20 + j];
    }
    float x = (j < 20) ? acc : 0.f;
    float s1 = x, s2 = x * x;
    #pragma unroll
    for (int off = 32; off > 0; off >>= 1) {
        s1 += __shfl_xor(s1, off);
        s2 += __shfl_xor(s2, off);
    }
    float mu = s1 * (1.0f / 20.0f);
    float var = s2 * (1.0f / 20.0f) - mu * mu;
    if (j < 20) {
        float y = (acc - mu) * rsqrtf(var + 1e-5f) * gp[j] + betap[j];
        npj[(size_t)v * 20 + j] = fmaxf(y, 0.f);
    }
}

// ---------------------------------------------------------------- CSR build
__global__ __launch_bounds__(256) void deg_kernel(const int* __restrict__ dst, int* __restrict__ deg, int E) {
    int e = blockIdx.x * 256 + threadIdx.x;
    if (e < E) atomicAdd(&deg[dst[e]], 1);
}

__global__ __launch_bounds__(1024) void scan_kernel(const int* __restrict__ deg, int* __restrict__ row, int V) {
    __shared__ int wsum[16];
    __shared__ int carry_sh;
    int t = threadIdx.x, lane = t & 63, wid = t >> 6;
    if (t == 0) carry_sh = 0;
    __syncthreads();
    for (int base = 0; base < V; base += 1024) {
        int i = base + t;
        int val = (i < V) ? deg[i] : 0;
        #pragma unroll
        for (int s = 1; s < 64; s <<= 1) {
            int n = __shfl_up(val, s);
            if (lane >= s) val += n;
        }
        if (lane == 63) wsum[wid] = val;
        __syncthreads();
        if (wid == 0) {
            int x = (lane < 16) ? wsum[lane] : 0;
            #pragma unroll
            for (int s = 1; s < 16; s <<= 1) {
                int n = __shfl_up(x, s);
                if (lane >= s) x += n;
            }
            if (lane < 16) wsum[lane] = x;
        }
        __syncthreads();
        int wprefix = (wid > 0) ? wsum[wid - 1] : 0;
        int c = carry_sh;
        int incl = c + wprefix + val;
        if (i < V) row[i + 1] = incl;
        __syncthreads();
        if (t == 1023) carry_sh = incl;
    }
    if (t == 0) row[0] = 0;
}

__global__ __launch_bounds__(256) void scatter_kernel(
    const int* __restrict__ dst, const int* __restrict__ row,
    int* __restrict__ cnt, int* __restrict__ eorder, int E)
{
    int e = blockIdx.x * 256 + threadIdx.x;
    if (e < E) {
        int d = dst[e];
        int pos = row[d] + atomicAdd(&cnt[d], 1);
        eorder[pos] = e;
    }
}

// ---------------------------------------------------------------- edge logits
__global__ __launch_bounds__(256) void logit_kernel(
    const float* __restrict__ nf, const int* __restrict__ src, const int* __restrict__ dst,
    const float* __restrict__ We, const float* __restrict__ be,
    float* __restrict__ logit, int E)
{
    int wid = threadIdx.x >> 6, lane = threadIdx.x & 63;
    int e = blockIdx.x * 4 + wid;
    if (e >= E) return;
    int d = dst[e], s = src[e];
    const float* row = (lane < 32) ? (nf + (size_t)d * 256) : (nf + (size_t)s * 256 - 256);
    int i = lane * 8;
    float4 x0 = *(const float4*)(row + i);
    float4 x1 = *(const float4*)(row + i + 4);
    float4 w0 = *(const float4*)(We + i);
    float4 w1 = *(const float4*)(We + i + 4);
    float sum = x0.x * w0.x + x0.y * w0.y + x0.z * w0.z + x0.w * w0.w
              + x1.x * w1.x + x1.y * w1.y + x1.z * w1.z + x1.w * w1.w;
    #pragma unroll
    for (int off = 32; off > 0; off >>= 1) sum += __shfl_xor(sum, off);
    if (lane == 0) logit[e] = fmaxf(sum + be[0], 0.f);
}

// ---------------------------------------------------------------- kron branch -> bf16 into acat[:,256:512]
__global__ __launch_bounds__(256) void kron_kernel(
    const float* __restrict__ npj, const int* __restrict__ srcArr,
    const int* __restrict__ eorder, const int* __restrict__ rowPtr,
    const float* __restrict__ Wk, const float* __restrict__ bk,
    const float* __restrict__ gkv, const float* __restrict__ betak,
    ushort* __restrict__ acat, int V)
{
    __shared__ __hip_bfloat16 T[KG * 20 * 256];   // 40 KB
    __shared__ float dsh[KG * 20];
    int t = threadIdx.x;
    int v0 = blockIdx.x * KG;

    if (t < KG * 20) {
        int g = t / 20, k = t % 20;
        int v = v0 + g;
        dsh[t] = (v < V) ? npj[(size_t)v * 20 + k] : 0.f;
    }
    __syncthreads();

    float dreg[KG][20];
    #pragma unroll
    for (int g = 0; g < KG; ++g)
        #pragma unroll
        for (int k = 0; k < 20; ++k) dreg[g][k] = dsh[g * 20 + k];

    for (int a = 0; a < 20; ++a) {
        float wv[20];
        #pragma unroll
        for (int k = 0; k < 20; ++k) wv[k] = Wk[(size_t)(a * 20 + k) * 256 + t];
        #pragma unroll
        for (int g = 0; g < KG; ++g) {
            float s = 0.f;
            #pragma unroll
            for (int k = 0; k < 20; ++k) s += dreg[g][k] * wv[k];
            T[(g * 20 + a) * 256 + t] = __float2bfloat16(s);
        }
    }
    __syncthreads();

    int wid = t >> 6, lane = t & 63;
    int v = v0 + wid;
    if (v >= V) return;
    int c0 = lane * 4;

    float Tr[20][4];
    #pragma unroll
    for (int a = 0; a < 20; ++a) {
        const __hip_bfloat16* tp = &T[(wid * 20 + a) * 256 + c0];
        Tr[a][0] = __bfloat162float(tp[0]);
        Tr[a][1] = __bfloat162float(tp[1]);
        Tr[a][2] = __bfloat162float(tp[2]);
        Tr[a][3] = __bfloat162float(tp[3]);
    }
    float4 bkv = *(const float4*)(bk + c0);
    float4 gk4 = *(const float4*)(gkv + c0);
    float4 bt4 = *(const float4*)(betak + c0);

    float acc0 = 0.f, acc1 = 0.f, acc2 = 0.f, acc3 = 0.f;
    int e0 = rowPtr[v], e1 = rowPtr[v + 1];
    for (int p = e0; p < e1; ++p) {
        int e = eorder[p];
        int sv = srcArr[e];
        float sval = (lane < 20) ? npj[(size_t)sv * 20 + lane] : 0.f;
        float y0 = bkv.x, y1 = bkv.y, y2 = bkv.z, y3 = bkv.w;
        #pragma unroll
        for (int a = 0; a < 20; ++a) {
            float s_a = __shfl(sval, a);
            y0 += s_a * Tr[a][0];
            y1 += s_a * Tr[a][1];
            y2 += s_a * Tr[a][2];
            y3 += s_a * Tr[a][3];
        }
        float s1 = y0 + y1 + y2 + y3;
        float s2 = y0 * y0 + y1 * y1 + y2 * y2 + y3 * y3;
        #pragma unroll
        for (int off = 32; off > 0; off >>= 1) {
            s1 += __shfl_xor(s1, off);
            s2 += __shfl_xor(s2, off);
        }
        float mu = s1 * (1.0f / 256.0f);
        float var = s2 * (1.0f / 256.0f) - mu * mu;
        float rs = rsqrtf(var + 1e-5f);
        acc0 += fmaxf((y0 - mu) * rs * gk4.x + bt4.x, 0.f);
        acc1 += fmaxf((y1 - mu) * rs * gk4.y + bt4.y, 0.f);
        acc2 += fmaxf((y2 - mu) * rs * gk4.z + bt4.z, 0.f);
        acc3 += fmaxf((y3 - mu) * rs * gk4.w + bt4.w, 0.f);
    }
    ushort4 o;
    o.x = f2bf(acc0); o.y = f2bf(acc1); o.z = f2bf(acc2); o.w = f2bf(acc3);
    *(ushort4*)(acat + (size_t)v * 512 + 256 + c0) = o;
}

// ---------------------------------------------------------------- attention stats per dst
__global__ __launch_bounds__(256) void att_kernel(
    const float* __restrict__ logit, const int* __restrict__ eorder,
    const int* __restrict__ rowPtr, float* __restrict__ mArr, float* __restrict__ invArr, int V)
{
    int wid = threadIdx.x >> 6, lane = threadIdx.x & 63;
    int v = blockIdx.x * 4 + wid;
    if (v >= V) return;
    int e0 = rowPtr[v], e1 = rowPtr[v + 1];
    float m = -1e30f;
    for (int p = e0 + lane; p < e1; p += 64) m = fmaxf(m, logit[eorder[p]]);
    #pragma unroll
    for (int off = 32; off > 0; off >>= 1) m = fmaxf(m, __shfl_xor(m, off));
    float d = 0.f;
    for (int p = e0 + lane; p < e1; p += 64) d += expf(logit[eorder[p]] - m);
    #pragma unroll
    for (int off = 32; off > 0; off >>= 1) d += __shfl_xor(d, off);
    if (lane == 0) {
        mArr[v] = m;
        invArr[v] = (e1 > e0) ? (1.0f / d) : 0.f;
    }
}

// ---------------------------------------------------------------- weighted context -> bf16 ctx
__global__ __launch_bounds__(256) void ctx_kernel(
    const float* __restrict__ hv, const float* __restrict__ logit,
    const float* __restrict__ mArr, const float* __restrict__ invArr,
    const int* __restrict__ srcArr, const int* __restrict__ eorder,
    const int* __restrict__ rowPtr, ushort* __restrict__ ctx_bf, int V)
{
    int v = blockIdx.x;
    int t = threadIdx.x;
    int e0 = rowPtr[v], e1 = rowPtr[v + 1];
    float m = mArr[v], inv = invArr[v];
    float acc = 0.f;
    for (int p = e0; p < e1; ++p) {
        int e = eorder[p];
        float a = expf(logit[e] - m) * inv;
        acc += a * hv[(size_t)srcArr[e] * 256 + t];
    }
    ctx_bf[(size_t)v * 256 + t] = f2bf(fmaxf(acc, 0.f));
}

// ---------------------------------------------------------------- GRU gates + LN -> bf16 into acat[:,0:256]
__global__ __launch_bounds__(256) void gru_ln_kernel(
    const ushort* __restrict__ rz, const ushort* __restrict__ inb,
    const ushort* __restrict__ hnb, const float* __restrict__ nf,
    const float* __restrict__ g_ln, const float* __restrict__ b_ln,
    ushort* __restrict__ acat, int V)
{
    __shared__ float red[8];
    int v = blockIdx.x, t = threadIdx.x;
    float r = sigmoidf(bf2f(rz[(size_t)v * 512 + t]));
    float z = sigmoidf(bf2f(rz[(size_t)v * 512 + 256 + t]));
    float n = tanhf(bf2f(inb[(size_t)v * 256 + t]) + r * bf2f(hnb[(size_t)v * 256 + t]));
    float h = (1.f - z) * n + z * nf[(size_t)v * 256 + t];
    float x = fmaxf(h, 0.f);
    float s1 = x, s2 = x * x;
    blockSum2(s1, s2, red);
    float mu = s1 * (1.0f / 256.0f);
    float var = s2 * (1.0f / 256.0f) - mu * mu;
    float y = (x - mu) * rsqrtf(var + 1e-5f) * g_ln[t] + b_ln[t];
    acat[(size_t)v * 512 + t] = f2bf(y);
}

// ---------------------------------------------------------------- row LayerNorm over 256 (optional relu)
__global__ __launch_bounds__(256) void ln_kernel(
    const float* __restrict__ in, float* __restrict__ out,
    const float* __restrict__ g, const float* __restrict__ b, int relu_after)
{
    __shared__ float red[8];
    int v = blockIdx.x, t = threadIdx.x;
    float x = in[(size_t)v * 256 + t];
    float s1 = x, s2 = x * x;
    blockSum2(s1, s2, red);
    float mu = s1 * (1.0f / 256.0f);
    float var = s2 * (1.0f / 256.0f) - mu * mu;
    float y = (x - mu) * rsqrtf(var + 1e-5f) * g[t] + b[t];
    if (relu_after) y = fmaxf(y, 0.f);
    out[(size_t)v * 256 + t] = y;
}

// ---------------------------------------------------------------- launcher
extern "C" void kernel_launch(void* const* d_in, const int* in_sizes, int n_in,
                              void* d_out, int out_size, void* d_ws, size_t ws_size,
                              hipStream_t stream)
{
    const float* nf    = (const float*)d_in[0];
    const int*   src   = (const int*)d_in[1];
    const int*   dst   = (const int*)d_in[2];
    const float* Wp    = (const float*)d_in[3];
    const float* bp    = (const float*)d_in[4];
    const float* gp    = (const float*)d_in[5];
    const float* betap = (const float*)d_in[6];
    const float* Wk    = (const float*)d_in[7];
    const float* bk    = (const float*)d_in[8];
    const float* gk    = (const float*)d_in[9];
    const float* betak = (const float*)d_in[10];
    const float* We    = (const float*)d_in[11];
    const float* be    = (const float*)d_in[12];
    const float* Wn    = (const float*)d_in[13];
    const float* bn    = (const float*)d_in[14];
    const float* W_ih  = (const float*)d_in[15];
    const float* W_hh  = (const float*)d_in[16];
    const float* b_ih  = (const float*)d_in[17];
    const float* b_hh  = (const float*)d_in[18];
    const float* g_ln  = (const float*)d_in[19];
    const float* bt_ln = (const float*)d_in[20];
    const float* Wc    = (const float*)d_in[21];
    const float* bc    = (const float*)d_in[22];
    const float* gc    = (const float*)d_in[23];
    const float* betac = (const float*)d_in[24];

    int V = in_sizes[0] / 256;
    int E = in_sizes[1];

    char* w = (char*)d_ws;
    auto alloc = [&](size_t bytes) -> char* {
        char* p = w;
        w += (bytes + 255) & ~(size_t)255;
        return p;
    };
    float*  npj     = (float*)alloc((size_t)V * 20 * 4);
    // hv (fp32 [V,256]) aliased with acat (bf16 [V,512]) — hv dead after ctx_kernel
    char*   hv_acat = alloc((size_t)V * 256 * 4);
    float*  hv      = (float*)hv_acat;
    ushort* acat    = (ushort*)hv_acat;
    ushort* nf_bf   = (ushort*)alloc((size_t)V * 256 * 2);
    ushort* ctx_bf  = (ushort*)alloc((size_t)V * 256 * 2);
    ushort* rz_bf   = (ushort*)alloc((size_t)V * 512 * 2);
    ushort* in_bf   = (ushort*)alloc((size_t)V * 256 * 2);
    ushort* hn_bf   = (ushort*)alloc((size_t)V * 256 * 2);
    ushort* BTn     = (ushort*)alloc(65536 * 2);
    ushort* BTrz    = (ushort*)alloc(262144 * 2);
    ushort* BTin    = (ushort*)alloc(65536 * 2);
    ushort* BThn    = (ushort*)alloc(65536 * 2);
    ushort* BTc     = (ushort*)alloc(131072 * 2);
    float*  bias_rz = (float*)alloc(512 * 4);
    float*  logit   = (float*)alloc((size_t)E * 4);
    float*  mArr    = (float*)alloc((size_t)V * 4);
    float*  invArr  = (float*)alloc((size_t)V * 4);
    int*    deg     = (int*)alloc((size_t)V * 4);
    int*    cnt     = (int*)alloc((size_t)V * 4);
    int*    rowp    = (int*)alloc((size_t)(V + 1) * 4);
    int*    eorder  = (int*)alloc((size_t)E * 4);

    hipMemsetAsync(deg, 0, (size_t)V * 4, stream);
    hipMemsetAsync(cnt, 0, (size_t)V * 4, stream);

    int mt = (V + 127) / 128;   // M tiles

    cast_bf16_kernel<<<(V * 64 + 255) / 256, 256, 0, stream>>>(nf, nf_bf, V * 256);
    prep_w_kernel<<<(590336 + 255) / 256, 256, 0, stream>>>(
        Wn, W_ih, W_hh, Wc, b_ih, b_hh, BTn, BTrz, BTin, BThn, BTc, bias_rz);

    npj_kernel<<<V, 64, 0, stream>>>(nf, Wp, bp, gp, betap, npj, V);
    deg_kernel<<<(E + 255) / 256, 256, 0, stream>>>(dst, deg, E);
    scan_kernel<<<1, 1024, 0, stream>>>(deg, rowp, V);
    scatter_kernel<<<(E + 255) / 256, 256, 0, stream>>>(dst, rowp, cnt, eorder, E);
    logit_kernel<<<(E + 3) / 4, 256, 0, stream>>>(nf, src, dst, We, be, logit, E);

    // hv = nf @ Wn + bn   (fp32 out, consumed by ctx gather)
    mfma_gemm_kernel<<<dim3(mt, 2), 256, 0, stream>>>(
        nf_bf, nf_bf, 256, 256, BTn, bn, hv, 0, V, 256, 256, 256);
    att_kernel<<<(V + 3) / 4, 256, 0, stream>>>(logit, eorder, rowp, mArr, invArr, V);
    ctx_kernel<<<V, 256, 0, stream>>>(hv, logit, mArr, invArr, src, eorder, rowp, ctx_bf, V);

    // kron -> acat[:,256:512] (hv now dead)
    kron_kernel<<<(V + KG - 1) / KG, 256, 0, stream>>>(npj, src, eorder, rowp, Wk, bk, gk, betak, acat, V);

    // rz = [ctx|nf] @ [Wih_rz;Whh_rz]^T + (b_ih+b_hh)   (N=512, K=512)
    mfma_gemm_kernel<<<dim3(mt, 4), 256, 0, stream>>>(
        ctx_bf, nf_bf, 256, 256, BTrz, bias_rz, rz_bf, 1, V, 512, 512, 512);
    // i_n = ctx @ Wih_n^T + b_ih_n
    mfma_gemm_kernel<<<dim3(mt, 2), 256, 0, stream>>>(
        ctx_bf, ctx_bf, 256, 256, BTin, b_ih + 512, in_bf, 1, V, 256, 256, 256);
    // h_n = nf @ Whh_n^T + b_hh_n
    mfma_gemm_kernel<<<dim3(mt, 2), 256, 0, stream>>>(
        nf_bf, nf_bf, 256, 256, BThn, b_hh + 512, hn_bf, 1, V, 256, 256, 256);

    gru_ln_kernel<<<V, 256, 0, stream>>>(rz_bf, in_bf, hn_bf, nf, g_ln, bt_ln, acat, V);

    // final: d_out = LN(acat @ Wc + bc) with relu
    mfma_gemm_kernel<<<dim3(mt, 2), 256, 0, stream>>>(
        acat, acat, 512, 512, BTc, bc, (float*)d_out, 0, V, 256, 512, 256);
    ln_kernel<<<V, 256, 0, stream>>>((float*)d_out, (float*)d_out, gc, betac, 1);
}

// Round 4
// 1348.087 us; speedup vs baseline: 2.5768x; 1.3824x over previous
//
#include <hip/hip_runtime.h>
#include <hip/hip_bf16.h>
#include <math.h>

#define KG 4        // dst nodes per block in kron kernel (one per wave)
#define KCHUNK 128  // edges staged in LDS per kron chunk

typedef __attribute__((ext_vector_type(8))) short bfrag;   // 8 bf16 (4 VGPRs)
typedef __attribute__((ext_vector_type(4))) float cfrag;   // 4 fp32 acc

__device__ __forceinline__ ushort f2bf(float f) {
    __hip_bfloat16 h = __float2bfloat16(f);
    return *(ushort*)&h;
}
__device__ __forceinline__ float bf2f(ushort u) {
    __hip_bfloat16 h;
    *(ushort*)&h = u;
    return __bfloat162float(h);
}

// ---------------------------------------------------------------- helpers
__device__ __forceinline__ void blockSum2(float& s1, float& s2, float* red) {
    #pragma unroll
    for (int off = 32; off > 0; off >>= 1) {
        s1 += __shfl_xor(s1, off);
        s2 += __shfl_xor(s2, off);
    }
    int lane = threadIdx.x & 63, wid = threadIdx.x >> 6;
    if (lane == 0) { red[wid] = s1; red[4 + wid] = s2; }
    __syncthreads();
    s1 = red[0] + red[1] + red[2] + red[3];
    s2 = red[4] + red[5] + red[6] + red[7];
}

__device__ __forceinline__ float sigmoidf(float x) { return 1.0f / (1.0f + expf(-x)); }

// ---------------------------------------------------------------- bf16 cast
__global__ __launch_bounds__(256) void cast_bf16_kernel(
    const float* __restrict__ x, ushort* __restrict__ y, int n)
{
    int i = (blockIdx.x * 256 + threadIdx.x) * 4;
    if (i < n) {
        float4 v = *(const float4*)(x + i);
        ushort4 o;
        o.x = f2bf(v.x); o.y = f2bf(v.y); o.z = f2bf(v.z); o.w = f2bf(v.w);
        *(ushort4*)(y + i) = o;
    }
}

// ---------------------------------------------------------------- weight prep (bf16 B^T layouts)
__global__ __launch_bounds__(256) void prep_w_kernel(
    const float* __restrict__ Wn, const float* __restrict__ Wih,
    const float* __restrict__ Whh, const float* __restrict__ Wc,
    const float* __restrict__ b_ih, const float* __restrict__ b_hh,
    ushort* __restrict__ BTn, ushort* __restrict__ BTrz,
    ushort* __restrict__ BTin, ushort* __restrict__ BThn,
    ushort* __restrict__ BTc, float* __restrict__ bias_rz)
{
    int id = blockIdx.x * 256 + threadIdx.x;
    if (id < 262144) {
        int n = id >> 9, k = id & 511;
        float v = (k < 256) ? Wih[n * 256 + k] : Whh[n * 256 + k - 256];
        BTrz[id] = f2bf(v);
    } else if (id < 327680) {
        int j = id - 262144; int n = j >> 8, k = j & 255;
        BTin[j] = f2bf(Wih[(512 + n) * 256 + k]);
    } else if (id < 393216) {
        int j = id - 327680; int n = j >> 8, k = j & 255;
        BThn[j] = f2bf(Whh[(512 + n) * 256 + k]);
    } else if (id < 458752) {
        int j = id - 393216; int n = j >> 8, k = j & 255;
        BTn[j] = f2bf(Wn[k * 256 + n]);
    } else if (id < 589824) {
        int j = id - 458752; int n = j >> 9, k = j & 511;
        BTc[j] = f2bf(Wc[k * 256 + n]);
    } else if (id < 590336) {
        int n = id - 589824;
        bias_rz[n] = b_ih[n] + b_hh[n];
    }
}

// ---------------------------------------------------------------- generic bf16 MFMA GEMM (128x128, BK=64)
__global__ __launch_bounds__(256) void mfma_gemm_kernel(
    const ushort* __restrict__ A1, const ushort* __restrict__ A2, int ksplit, int lda,
    const ushort* __restrict__ B, const float* __restrict__ bias,
    void* __restrict__ Cout, int store_bf16,
    int M, int N, int K, int ldc)
{
    __shared__ ushort As[128 * 64];
    __shared__ ushort Bs[128 * 64];
    int t = threadIdx.x;
    int m0 = blockIdx.x * 128, n0 = blockIdx.y * 128;
    int w = t >> 6, lane = t & 63;
    int q = lane >> 4, r = lane & 15;
    int wm = (w & 1) * 64, wn = (w >> 1) * 64;

    cfrag acc[4][4] = {};

    int srow_base = t >> 3;
    int skc = t & 7;

    for (int k0 = 0; k0 < K; k0 += 64) {
        const ushort* Ap; int kb;
        if (k0 < ksplit) { Ap = A1; kb = k0; } else { Ap = A2; kb = k0 - ksplit; }
        int4 av[4], bv[4];
        #pragma unroll
        for (int i = 0; i < 4; ++i) {
            int row = i * 32 + srow_base;
            int grow = m0 + row;
            av[i] = make_int4(0, 0, 0, 0);
            if (grow < M) av[i] = *(const int4*)(Ap + (size_t)grow * lda + kb + skc * 8);
            bv[i] = *(const int4*)(B + (size_t)(n0 + row) * K + k0 + skc * 8);
        }
        __syncthreads();
        #pragma unroll
        for (int i = 0; i < 4; ++i) {
            int row = i * 32 + srow_base;
            int off = row * 64 + ((skc ^ (row & 7)) * 8);
            *(int4*)&As[off] = av[i];
            *(int4*)&Bs[off] = bv[i];
        }
        __syncthreads();
        #pragma unroll
        for (int s = 0; s < 2; ++s) {
            bfrag af[4], bfr[4];
            int kc = s * 4 + q;
            #pragma unroll
            for (int mi = 0; mi < 4; ++mi) {
                int arow = wm + mi * 16 + r;
                af[mi] = *(const bfrag*)&As[arow * 64 + ((kc ^ (arow & 7)) * 8)];
            }
            #pragma unroll
            for (int ni = 0; ni < 4; ++ni) {
                int brow = wn + ni * 16 + r;
                bfr[ni] = *(const bfrag*)&Bs[brow * 64 + ((kc ^ (brow & 7)) * 8)];
            }
            #pragma unroll
            for (int mi = 0; mi < 4; ++mi)
                #pragma unroll
                for (int ni = 0; ni < 4; ++ni)
                    acc[mi][ni] = __builtin_amdgcn_mfma_f32_16x16x32_bf16(
                        af[mi], bfr[ni], acc[mi][ni], 0, 0, 0);
        }
    }

    float bvld[4];
    #pragma unroll
    for (int ni = 0; ni < 4; ++ni) bvld[ni] = bias[n0 + wn + ni * 16 + r];
    #pragma unroll
    for (int mi = 0; mi < 4; ++mi) {
        #pragma unroll
        for (int v = 0; v < 4; ++v) {
            int grow = m0 + wm + mi * 16 + q * 4 + v;
            if (grow >= M) continue;
            #pragma unroll
            for (int ni = 0; ni < 4; ++ni) {
                int gcol = n0 + wn + ni * 16 + r;
                float val = acc[mi][ni][v] + bvld[ni];
                if (store_bf16) ((ushort*)Cout)[(size_t)grow * ldc + gcol] = f2bf(val);
                else            ((float*)Cout)[(size_t)grow * ldc + gcol] = val;
            }
        }
    }
}

// ---------------------------------------------------------------- npj = relu(LN(nf@Wp + bp))
__global__ __launch_bounds__(64) void npj_kernel(
    const float* __restrict__ nf, const float* __restrict__ Wp,
    const float* __restrict__ bp, const float* __restrict__ gp,
    const float* __restrict__ betap, float* __restrict__ npj, int V)
{
    int v = blockIdx.x;
    int j = threadIdx.x;
    float acc = 0.f;
    if (j < 20) {
        acc = bp[j];
        const float* row = nf + (size_t)v * 256;
        #pragma unroll 8
        for (int i = 0; i < 256; ++i) acc += row[i] * Wp[i * 20 + j];
    }
    float x = (j < 20) ? acc : 0.f;
    float s1 = x, s2 = x * x;
    #pragma unroll
    for (int off = 32; off > 0; off >>= 1) {
        s1 += __shfl_xor(s1, off);
        s2 += __shfl_xor(s2, off);
    }
    float mu = s1 * (1.0f / 20.0f);
    float var = s2 * (1.0f / 20.0f) - mu * mu;
    if (j < 20) {
        float y = (acc - mu) * rsqrtf(var + 1e-5f) * gp[j] + betap[j];
        npj[(size_t)v * 20 + j] = fmaxf(y, 0.f);
    }
}

// ---------------------------------------------------------------- CSR build
__global__ __launch_bounds__(256) void deg_kernel(const int* __restrict__ dst, int* __restrict__ deg, int E) {
    int e = blockIdx.x * 256 + threadIdx.x;
    if (e < E) atomicAdd(&deg[dst[e]], 1);
}

__global__ __launch_bounds__(1024) void scan_kernel(const int* __restrict__ deg, int* __restrict__ row, int V) {
    __shared__ int wsum[16];
    __shared__ int carry_sh;
    int t = threadIdx.x, lane = t & 63, wid = t >> 6;
    if (t == 0) carry_sh = 0;
    __syncthreads();
    for (int base = 0; base < V; base += 1024) {
        int i = base + t;
        int val = (i < V) ? deg[i] : 0;
        #pragma unroll
        for (int s = 1; s < 64; s <<= 1) {
            int n = __shfl_up(val, s);
            if (lane >= s) val += n;
        }
        if (lane == 63) wsum[wid] = val;
        __syncthreads();
        if (wid == 0) {
            int x = (lane < 16) ? wsum[lane] : 0;
            #pragma unroll
            for (int s = 1; s < 16; s <<= 1) {
                int n = __shfl_up(x, s);
                if (lane >= s) x += n;
            }
            if (lane < 16) wsum[lane] = x;
        }
        __syncthreads();
        int wprefix = (wid > 0) ? wsum[wid - 1] : 0;
        int c = carry_sh;
        int incl = c + wprefix + val;
        if (i < V) row[i + 1] = incl;
        __syncthreads();
        if (t == 1023) carry_sh = incl;
    }
    if (t == 0) row[0] = 0;
}

__global__ __launch_bounds__(256) void scatter_kernel(
    const int* __restrict__ dst, const int* __restrict__ row,
    int* __restrict__ cnt, int* __restrict__ eorder, int E)
{
    int e = blockIdx.x * 256 + threadIdx.x;
    if (e < E) {
        int d = dst[e];
        int pos = row[d] + atomicAdd(&cnt[d], 1);
        eorder[pos] = e;
    }
}

// ---------------------------------------------------------------- per-node edge-logit projections
// pd[v] = dot(nf[v], We[0:256]); ps[v] = dot(nf[v], We[256:512])  (he = [nf[dst], nf[src]])
__global__ __launch_bounds__(256) void nodeproj_kernel(
    const float* __restrict__ nf, const float* __restrict__ We,
    float* __restrict__ pd, float* __restrict__ ps, int V)
{
    int wid = threadIdx.x >> 6, lane = threadIdx.x & 63;
    int v = blockIdx.x * 4 + wid;
    if (v >= V) return;
    const float* row = nf + (size_t)v * 256;
    int i = lane * 4;
    float4 x  = *(const float4*)(row + i);
    float4 wd = *(const float4*)(We + i);
    float4 wsv = *(const float4*)(We + 256 + i);
    float sd = x.x * wd.x + x.y * wd.y + x.z * wd.z + x.w * wd.w;
    float ss = x.x * wsv.x + x.y * wsv.y + x.z * wsv.z + x.w * wsv.w;
    #pragma unroll
    for (int off = 32; off > 0; off >>= 1) {
        sd += __shfl_xor(sd, off);
        ss += __shfl_xor(ss, off);
    }
    if (lane == 0) { pd[v] = sd; ps[v] = ss; }
}

// ---------------------------------------------------------------- edge prep (eorder order): logitOrd, srcOrd
__global__ __launch_bounds__(256) void edgeprep_kernel(
    const int* __restrict__ eorder, const int* __restrict__ src, const int* __restrict__ dst,
    const float* __restrict__ pd, const float* __restrict__ ps, const float* __restrict__ be,
    float* __restrict__ logitOrd, int* __restrict__ srcOrd, int E)
{
    int p = blockIdx.x * 256 + threadIdx.x;
    if (p < E) {
        int e = eorder[p];
        int s = src[e], d = dst[e];
        srcOrd[p] = s;
        logitOrd[p] = fmaxf(pd[d] + ps[s] + be[0], 0.f);
    }
}

// ---------------------------------------------------------------- kron branch
// Stage 1 (block-coop): T_g[a][o] -> LDS bf16.  Stage 2: chunked LDS prefetch of edge npj
// vectors (parallel gathers), then wave-private unrolled-x2 edge loop (LDS broadcast reads).
__global__ __launch_bounds__(256) void kron_kernel(
    const float* __restrict__ npj, const int* __restrict__ srcOrd,
    const int* __restrict__ rowPtr,
    const float* __restrict__ Wk, const float* __restrict__ bk,
    const float* __restrict__ gkv, const float* __restrict__ betak,
    ushort* __restrict__ acat, int V)
{
    __shared__ __hip_bfloat16 T[KG * 20 * 256];   // 40 KB
    __shared__ float dsh[KG * 20];
    __shared__ int sIdx[KCHUNK];
    __shared__ float sE[KCHUNK * 20];             // 10 KB
    int t = threadIdx.x;
    int v0 = blockIdx.x * KG;

    if (t < KG * 20) {
        int g = t / 20, k = t % 20;
        int v = v0 + g;
        dsh[t] = (v < V) ? npj[(size_t)v * 20 + k] : 0.f;
    }
    __syncthreads();

    float dreg[KG][20];
    #pragma unroll
    for (int g = 0; g < KG; ++g)
        #pragma unroll
        for (int k = 0; k < 20; ++k) dreg[g][k] = dsh[g * 20 + k];

    for (int a = 0; a < 20; ++a) {
        float wv[20];
        #pragma unroll
        for (int k = 0; k < 20; ++k) wv[k] = Wk[(size_t)(a * 20 + k) * 256 + t];
        #pragma unroll
        for (int g = 0; g < KG; ++g) {
            float s = 0.f;
            #pragma unroll
            for (int k = 0; k < 20; ++k) s += dreg[g][k] * wv[k];
            T[(g * 20 + a) * 256 + t] = __float2bfloat16(s);
        }
    }
    __syncthreads();

    int wid = t >> 6, lane = t & 63;
    int v = v0 + wid;
    int c0 = lane * 4;

    float Tr[20][4];
    #pragma unroll
    for (int a = 0; a < 20; ++a) {
        const __hip_bfloat16* tp = &T[(wid * 20 + a) * 256 + c0];
        Tr[a][0] = __bfloat162float(tp[0]);
        Tr[a][1] = __bfloat162float(tp[1]);
        Tr[a][2] = __bfloat162float(tp[2]);
        Tr[a][3] = __bfloat162float(tp[3]);
    }
    float4 bkv = *(const float4*)(bk + c0);
    float4 gk4 = *(const float4*)(gkv + c0);
    float4 bt4 = *(const float4*)(betak + c0);

    int eBase = rowPtr[v0];
    int vEnd = (v0 + KG < V) ? (v0 + KG) : V;
    int eEndB = rowPtr[vEnd];
    int myE0 = (v < V) ? rowPtr[v] : 0;
    int myE1 = (v < V) ? rowPtr[v + 1] : 0;

    float a0 = 0.f, a1 = 0.f, a2 = 0.f, a3 = 0.f;

    for (int base = eBase; base < eEndB; base += KCHUNK) {
        int nC = eEndB - base; if (nC > KCHUNK) nC = KCHUNK;
        __syncthreads();   // previous chunk fully consumed
        for (int i = t; i < nC; i += 256) sIdx[i] = srcOrd[base + i];
        __syncthreads();
        for (int idx = t; idx < nC * 20; idx += 256) {
            int le = idx / 20, aa = idx - le * 20;
            sE[idx] = npj[(size_t)sIdx[le] * 20 + aa];
        }
        __syncthreads();

        int lo = (myE0 > base) ? myE0 : base;
        int hi = (myE1 < base + nC) ? myE1 : base + nC;
        int p = lo;
        for (; p + 1 < hi; p += 2) {
            const float* sa = &sE[(p - base) * 20];
            const float* sb = &sE[(p + 1 - base) * 20];
            float ya0 = bkv.x, ya1 = bkv.y, ya2 = bkv.z, ya3 = bkv.w;
            float yb0 = bkv.x, yb1 = bkv.y, yb2 = bkv.z, yb3 = bkv.w;
            #pragma unroll
            for (int a = 0; a < 20; ++a) {
                float va = sa[a], vb = sb[a];
                ya0 += va * Tr[a][0]; ya1 += va * Tr[a][1];
                ya2 += va * Tr[a][2]; ya3 += va * Tr[a][3];
                yb0 += vb * Tr[a][0]; yb1 += vb * Tr[a][1];
                yb2 += vb * Tr[a][2]; yb3 += vb * Tr[a][3];
            }
            float s1a = ya0 + ya1 + ya2 + ya3;
            float s2a = ya0 * ya0 + ya1 * ya1 + ya2 * ya2 + ya3 * ya3;
            float s1b = yb0 + yb1 + yb2 + yb3;
            float s2b = yb0 * yb0 + yb1 * yb1 + yb2 * yb2 + yb3 * yb3;
            #pragma unroll
            for (int off = 32; off > 0; off >>= 1) {
                s1a += __shfl_xor(s1a, off);
                s2a += __shfl_xor(s2a, off);
                s1b += __shfl_xor(s1b, off);
                s2b += __shfl_xor(s2b, off);
            }
            float mua = s1a * (1.0f / 256.0f);
            float rsa = rsqrtf(s2a * (1.0f / 256.0f) - mua * mua + 1e-5f);
            float mub = s1b * (1.0f / 256.0f);
            float rsb = rsqrtf(s2b * (1.0f / 256.0f) - mub * mub + 1e-5f);
            a0 += fmaxf((ya0 - mua) * rsa * gk4.x + bt4.x, 0.f) + fmaxf((yb0 - mub) * rsb * gk4.x + bt4.x, 0.f);
            a1 += fmaxf((ya1 - mua) * rsa * gk4.y + bt4.y, 0.f) + fmaxf((yb1 - mub) * rsb * gk4.y + bt4.y, 0.f);
            a2 += fmaxf((ya2 - mua) * rsa * gk4.z + bt4.z, 0.f) + fmaxf((yb2 - mub) * rsb * gk4.z + bt4.z, 0.f);
            a3 += fmaxf((ya3 - mua) * rsa * gk4.w + bt4.w, 0.f) + fmaxf((yb3 - mub) * rsb * gk4.w + bt4.w, 0.f);
        }
        if (p < hi) {
            const float* sa = &sE[(p - base) * 20];
            float ya0 = bkv.x, ya1 = bkv.y, ya2 = bkv.z, ya3 = bkv.w;
            #pragma unroll
            for (int a = 0; a < 20; ++a) {
                float va = sa[a];
                ya0 += va * Tr[a][0]; ya1 += va * Tr[a][1];
                ya2 += va * Tr[a][2]; ya3 += va * Tr[a][3];
            }
            float s1a = ya0 + ya1 + ya2 + ya3;
            float s2a = ya0 * ya0 + ya1 * ya1 + ya2 * ya2 + ya3 * ya3;
            #pragma unroll
            for (int off = 32; off > 0; off >>= 1) {
                s1a += __shfl_xor(s1a, off);
                s2a += __shfl_xor(s2a, off);
            }
            float mua = s1a * (1.0f / 256.0f);
            float rsa = rsqrtf(s2a * (1.0f / 256.0f) - mua * mua + 1e-5f);
            a0 += fmaxf((ya0 - mua) * rsa * gk4.x + bt4.x, 0.f);
            a1 += fmaxf((ya1 - mua) * rsa * gk4.y + bt4.y, 0.f);
            a2 += fmaxf((ya2 - mua) * rsa * gk4.z + bt4.z, 0.f);
            a3 += fmaxf((ya3 - mua) * rsa * gk4.w + bt4.w, 0.f);
        }
    }
    if (v < V) {
        ushort4 o;
        o.x = f2bf(a0); o.y = f2bf(a1); o.z = f2bf(a2); o.w = f2bf(a3);
        *(ushort4*)(acat + (size_t)v * 512 + 256 + c0) = o;
    }
}

// ---------------------------------------------------------------- attention stats per dst (linear reads)
__global__ __launch_bounds__(256) void att_kernel(
    const float* __restrict__ logitOrd, const int* __restrict__ rowPtr,
    float* __restrict__ mArr, float* __restrict__ invArr, int V)
{
    int wid = threadIdx.x >> 6, lane = threadIdx.x & 63;
    int v = blockIdx.x * 4 + wid;
    if (v >= V) return;
    int e0 = rowPtr[v], e1 = rowPtr[v + 1];
    float m = -1e30f;
    for (int p = e0 + lane; p < e1; p += 64) m = fmaxf(m, logitOrd[p]);
    #pragma unroll
    for (int off = 32; off > 0; off >>= 1) m = fmaxf(m, __shfl_xor(m, off));
    float d = 0.f;
    for (int p = e0 + lane; p < e1; p += 64) d += expf(logitOrd[p] - m);
    #pragma unroll
    for (int off = 32; off > 0; off >>= 1) d += __shfl_xor(d, off);
    if (lane == 0) {
        mArr[v] = m;
        invArr[v] = (e1 > e0) ? (1.0f / d) : 0.f;
    }
}

// ---------------------------------------------------------------- weighted context (bf16 hv, unroll x4)
__global__ __launch_bounds__(256) void ctx_kernel(
    const ushort* __restrict__ hv_bf, const float* __restrict__ logitOrd,
    const float* __restrict__ mArr, const float* __restrict__ invArr,
    const int* __restrict__ srcOrd, const int* __restrict__ rowPtr,
    ushort* __restrict__ ctx_bf, int V)
{
    int v = blockIdx.x;
    int t = threadIdx.x;
    int e0 = rowPtr[v], e1 = rowPtr[v + 1];
    float m = mArr[v], inv = invArr[v];
    float acc = 0.f;
    int p = e0;
    for (; p + 3 < e1; p += 4) {
        int s0 = srcOrd[p], s1 = srcOrd[p + 1], s2 = srcOrd[p + 2], s3 = srcOrd[p + 3];
        float w0 = expf(logitOrd[p] - m) * inv;
        float w1 = expf(logitOrd[p + 1] - m) * inv;
        float w2 = expf(logitOrd[p + 2] - m) * inv;
        float w3 = expf(logitOrd[p + 3] - m) * inv;
        float h0 = bf2f(hv_bf[(size_t)s0 * 256 + t]);
        float h1 = bf2f(hv_bf[(size_t)s1 * 256 + t]);
        float h2 = bf2f(hv_bf[(size_t)s2 * 256 + t]);
        float h3 = bf2f(hv_bf[(size_t)s3 * 256 + t]);
        acc += w0 * h0 + w1 * h1 + w2 * h2 + w3 * h3;
    }
    for (; p < e1; ++p) {
        float wgt = expf(logitOrd[p] - m) * inv;
        acc += wgt * bf2f(hv_bf[(size_t)srcOrd[p] * 256 + t]);
    }
    ctx_bf[(size_t)v * 256 + t] = f2bf(fmaxf(acc, 0.f));
}

// ---------------------------------------------------------------- GRU gates + LN -> bf16 into acat[:,0:256]
__global__ __launch_bounds__(256) void gru_ln_kernel(
    const ushort* __restrict__ rz, const ushort* __restrict__ inb,
    const ushort* __restrict__ hnb, const float* __restrict__ nf,
    const float* __restrict__ g_ln, const float* __restrict__ b_ln,
    ushort* __restrict__ acat, int V)
{
    __shared__ float red[8];
    int v = blockIdx.x, t = threadIdx.x;
    float r = sigmoidf(bf2f(rz[(size_t)v * 512 + t]));
    float z = sigmoidf(bf2f(rz[(size_t)v * 512 + 256 + t]));
    float n = tanhf(bf2f(inb[(size_t)v * 256 + t]) + r * bf2f(hnb[(size_t)v * 256 + t]));
    float h = (1.f - z) * n + z * nf[(size_t)v * 256 + t];
    float x = fmaxf(h, 0.f);
    float s1 = x, s2 = x * x;
    blockSum2(s1, s2, red);
    float mu = s1 * (1.0f / 256.0f);
    float var = s2 * (1.0f / 256.0f) - mu * mu;
    float y = (x - mu) * rsqrtf(var + 1e-5f) * g_ln[t] + b_ln[t];
    acat[(size_t)v * 512 + t] = f2bf(y);
}

// ---------------------------------------------------------------- row LayerNorm (optional relu)
__global__ __launch_bounds__(256) void ln_kernel(
    const float* __restrict__ in, float* __restrict__ out,
    const float* __restrict__ g, const float* __restrict__ b, int relu_after)
{
    __shared__ float red[8];
    int v = blockIdx.x, t = threadIdx.x;
    float x = in[(size_t)v * 256 + t];
    float s1 = x, s2 = x * x;
    blockSum2(s1, s2, red);
    float mu = s1 * (1.0f / 256.0f);
    float var = s2 * (1.0f / 256.0f) - mu * mu;
    float y = (x - mu) * rsqrtf(var + 1e-5f) * g[t] + b[t];
    if (relu_after) y = fmaxf(y, 0.f);
    out[(size_t)v * 256 + t] = y;
}

// ---------------------------------------------------------------- launcher
extern "C" void kernel_launch(void* const* d_in, const int* in_sizes, int n_in,
                              void* d_out, int out_size, void* d_ws, size_t ws_size,
                              hipStream_t stream)
{
    const float* nf    = (const float*)d_in[0];
    const int*   src   = (const int*)d_in[1];
    const int*   dst   = (const int*)d_in[2];
    const float* Wp    = (const float*)d_in[3];
    const float* bp    = (const float*)d_in[4];
    const float* gp    = (const float*)d_in[5];
    const float* betap = (const float*)d_in[6];
    const float* Wk    = (const float*)d_in[7];
    const float* bk    = (const float*)d_in[8];
    const float* gk    = (const float*)d_in[9];
    const float* betak = (const float*)d_in[10];
    const float* We    = (const float*)d_in[11];
    const float* be    = (const float*)d_in[12];
    const float* Wn    = (const float*)d_in[13];
    const float* bn    = (const float*)d_in[14];
    const float* W_ih  = (const float*)d_in[15];
    const float* W_hh  = (const float*)d_in[16];
    const float* b_ih  = (const float*)d_in[17];
    const float* b_hh  = (const float*)d_in[18];
    const float* g_ln  = (const float*)d_in[19];
    const float* bt_ln = (const float*)d_in[20];
    const float* Wc    = (const float*)d_in[21];
    const float* bc    = (const float*)d_in[22];
    const float* gc    = (const float*)d_in[23];
    const float* betac = (const float*)d_in[24];

    int V = in_sizes[0] / 256;
    int E = in_sizes[1];

    char* w = (char*)d_ws;
    auto alloc = [&](size_t bytes) -> char* {
        char* p = w;
        w += (bytes + 255) & ~(size_t)255;
        return p;
    };
    float*  npj      = (float*)alloc((size_t)V * 20 * 4);
    ushort* acat     = (ushort*)alloc((size_t)V * 512 * 2);
    ushort* nf_bf    = (ushort*)alloc((size_t)V * 256 * 2);
    ushort* ctx_bf   = (ushort*)alloc((size_t)V * 256 * 2);
    ushort* rz_bf    = (ushort*)alloc((size_t)V * 512 * 2);
    ushort* hv_bf    = rz_bf;  // alias: hv dead before rz GEMM writes
    ushort* in_bf    = (ushort*)alloc((size_t)V * 256 * 2);
    ushort* hn_bf    = (ushort*)alloc((size_t)V * 256 * 2);
    ushort* BTn      = (ushort*)alloc(65536 * 2);
    ushort* BTrz     = (ushort*)alloc(262144 * 2);
    ushort* BTin     = (ushort*)alloc(65536 * 2);
    ushort* BThn     = (ushort*)alloc(65536 * 2);
    ushort* BTc      = (ushort*)alloc(131072 * 2);
    float*  bias_rz  = (float*)alloc(512 * 4);
    float*  logitOrd = (float*)alloc((size_t)E * 4);
    int*    srcOrd   = (int*)alloc((size_t)E * 4);
    float*  pd       = (float*)alloc((size_t)V * 4);
    float*  ps       = (float*)alloc((size_t)V * 4);
    float*  mArr     = (float*)alloc((size_t)V * 4);
    float*  invArr   = (float*)alloc((size_t)V * 4);
    int*    deg      = (int*)alloc((size_t)V * 4);
    int*    cnt      = (int*)alloc((size_t)V * 4);
    int*    rowp     = (int*)alloc((size_t)(V + 1) * 4);
    int*    eorder   = (int*)alloc((size_t)E * 4);

    hipMemsetAsync(deg, 0, (size_t)V * 4, stream);
    hipMemsetAsync(cnt, 0, (size_t)V * 4, stream);

    int mt = (V + 127) / 128;

    cast_bf16_kernel<<<(V * 64 + 255) / 256, 256, 0, stream>>>(nf, nf_bf, V * 256);
    prep_w_kernel<<<(590336 + 255) / 256, 256, 0, stream>>>(
        Wn, W_ih, W_hh, Wc, b_ih, b_hh, BTn, BTrz, BTin, BThn, BTc, bias_rz);

    npj_kernel<<<V, 64, 0, stream>>>(nf, Wp, bp, gp, betap, npj, V);
    deg_kernel<<<(E + 255) / 256, 256, 0, stream>>>(dst, deg, E);
    scan_kernel<<<1, 1024, 0, stream>>>(deg, rowp, V);
    scatter_kernel<<<(E + 255) / 256, 256, 0, stream>>>(dst, rowp, cnt, eorder, E);
    nodeproj_kernel<<<(V + 3) / 4, 256, 0, stream>>>(nf, We, pd, ps, V);
    edgeprep_kernel<<<(E + 255) / 256, 256, 0, stream>>>(
        eorder, src, dst, pd, ps, be, logitOrd, srcOrd, E);

    // hv = nf @ Wn + bn  -> bf16 (aliased on rz_bf; consumed by ctx before rz GEMM)
    mfma_gemm_kernel<<<dim3(mt, 2), 256, 0, stream>>>(
        nf_bf, nf_bf, 256, 256, BTn, bn, hv_bf, 1, V, 256, 256, 256);
    att_kernel<<<(V + 3) / 4, 256, 0, stream>>>(logitOrd, rowp, mArr, invArr, V);
    ctx_kernel<<<V, 256, 0, stream>>>(hv_bf, logitOrd, mArr, invArr, srcOrd, rowp, ctx_bf, V);

    kron_kernel<<<(V + KG - 1) / KG, 256, 0, stream>>>(
        npj, srcOrd, rowp, Wk, bk, gk, betak, acat, V);

    // rz = [ctx|nf] @ BTrz + (b_ih+b_hh)
    mfma_gemm_kernel<<<dim3(mt, 4), 256, 0, stream>>>(
        ctx_bf, nf_bf, 256, 256, BTrz, bias_rz, rz_bf, 1, V, 512, 512, 512);
    mfma_gemm_kernel<<<dim3(mt, 2), 256, 0, stream>>>(
        ctx_bf, ctx_bf, 256, 256, BTin, b_ih + 512, in_bf, 1, V, 256, 256, 256);
    mfma_gemm_kernel<<<dim3(mt, 2), 256, 0, stream>>>(
        nf_bf, nf_bf, 256, 256, BThn, b_hh + 512, hn_bf, 1, V, 256, 256, 256);

    gru_ln_kernel<<<V, 256, 0, stream>>>(rz_bf, in_bf, hn_bf, nf, g_ln, bt_ln, acat, V);

    mfma_gemm_kernel<<<dim3(mt, 2), 256, 0, stream>>>(
        acat, acat, 512, 512, BTc, bc, (float*)d_out, 0, V, 256, 512, 256);
    ln_kernel<<<V, 256, 0, stream>>>((float*)d_out, (float*)d_out, gc, betac, 1);
}

// Round 5
// 1266.011 us; speedup vs baseline: 2.7438x; 1.0648x over previous
//
#include <hip/hip_runtime.h>
#include <hip/hip_bf16.h>
#include <math.h>

#define KG 4        // dst nodes per block in kron kernel (one per wave)
#define KCHUNK 128  // edges staged in LDS per kron chunk

typedef __attribute__((ext_vector_type(8))) short bfrag;   // 8 bf16 (4 VGPRs)
typedef __attribute__((ext_vector_type(4))) float cfrag;   // 4 fp32 acc

__device__ __forceinline__ ushort f2bf(float f) {
    __hip_bfloat16 h = __float2bfloat16(f);
    return *(ushort*)&h;
}
__device__ __forceinline__ float bf2f(ushort u) {
    __hip_bfloat16 h;
    *(ushort*)&h = u;
    return __bfloat162float(h);
}

// ---------------------------------------------------------------- helpers
__device__ __forceinline__ void blockSum2(float& s1, float& s2, float* red) {
    #pragma unroll
    for (int off = 32; off > 0; off >>= 1) {
        s1 += __shfl_xor(s1, off);
        s2 += __shfl_xor(s2, off);
    }
    int lane = threadIdx.x & 63, wid = threadIdx.x >> 6;
    if (lane == 0) { red[wid] = s1; red[4 + wid] = s2; }
    __syncthreads();
    s1 = red[0] + red[1] + red[2] + red[3];
    s2 = red[4] + red[5] + red[6] + red[7];
}

// VALU-only full-wave sum: DPP row_shr 1/2/4/8 + row_bcast15/31, result broadcast
// via readlane(63). No DS-pipe traffic (vs ds_swizzle butterfly).
__device__ __forceinline__ float dppWaveSum(float x) {
    float t;
    t = __int_as_float(__builtin_amdgcn_update_dpp(0, __float_as_int(x), 0x111, 0xf, 0xf, true)); x += t;
    t = __int_as_float(__builtin_amdgcn_update_dpp(0, __float_as_int(x), 0x112, 0xf, 0xf, true)); x += t;
    t = __int_as_float(__builtin_amdgcn_update_dpp(0, __float_as_int(x), 0x114, 0xf, 0xf, true)); x += t;
    t = __int_as_float(__builtin_amdgcn_update_dpp(0, __float_as_int(x), 0x118, 0xf, 0xf, true)); x += t;
    t = __int_as_float(__builtin_amdgcn_update_dpp(0, __float_as_int(x), 0x142, 0xf, 0xf, true)); x += t;
    t = __int_as_float(__builtin_amdgcn_update_dpp(0, __float_as_int(x), 0x143, 0xf, 0xf, true)); x += t;
    return __int_as_float(__builtin_amdgcn_readlane(__float_as_int(x), 63));
}

__device__ __forceinline__ float sigmoidf(float x) { return 1.0f / (1.0f + expf(-x)); }

// ---------------------------------------------------------------- bf16 cast
__global__ __launch_bounds__(256) void cast_bf16_kernel(
    const float* __restrict__ x, ushort* __restrict__ y, int n)
{
    int i = (blockIdx.x * 256 + threadIdx.x) * 4;
    if (i < n) {
        float4 v = *(const float4*)(x + i);
        ushort4 o;
        o.x = f2bf(v.x); o.y = f2bf(v.y); o.z = f2bf(v.z); o.w = f2bf(v.w);
        *(ushort4*)(y + i) = o;
    }
}

// ---------------------------------------------------------------- weight prep (bf16 B^T layouts)
__global__ __launch_bounds__(256) void prep_w_kernel(
    const float* __restrict__ Wn, const float* __restrict__ Wih,
    const float* __restrict__ Whh, const float* __restrict__ Wc,
    const float* __restrict__ b_ih, const float* __restrict__ b_hh,
    const float* __restrict__ Wp, const float* __restrict__ bp,
    ushort* __restrict__ BTn, ushort* __restrict__ BTrz,
    ushort* __restrict__ BTin, ushort* __restrict__ BThn,
    ushort* __restrict__ BTc, float* __restrict__ bias_rz,
    ushort* __restrict__ BTp, float* __restrict__ bp_pad)
{
    int id = blockIdx.x * 256 + threadIdx.x;
    if (id < 262144) {
        int n = id >> 9, k = id & 511;
        float v = (k < 256) ? Wih[n * 256 + k] : Whh[n * 256 + k - 256];
        BTrz[id] = f2bf(v);
    } else if (id < 327680) {
        int j = id - 262144; int n = j >> 8, k = j & 255;
        BTin[j] = f2bf(Wih[(512 + n) * 256 + k]);
    } else if (id < 393216) {
        int j = id - 327680; int n = j >> 8, k = j & 255;
        BThn[j] = f2bf(Whh[(512 + n) * 256 + k]);
    } else if (id < 458752) {
        int j = id - 393216; int n = j >> 8, k = j & 255;
        BTn[j] = f2bf(Wn[k * 256 + n]);
    } else if (id < 589824) {
        int j = id - 458752; int n = j >> 9, k = j & 511;
        BTc[j] = f2bf(Wc[k * 256 + n]);
    } else if (id < 590336) {
        int n = id - 589824;
        bias_rz[n] = b_ih[n] + b_hh[n];
    } else if (id < 623104) {
        int j = id - 590336; int n = j >> 8, k = j & 255;
        BTp[j] = f2bf((n < 20) ? Wp[k * 20 + n] : 0.f);
    } else if (id < 623232) {
        int n = id - 623104;
        bp_pad[n] = (n < 20) ? bp[n] : 0.f;
    }
}

// ---------------------------------------------------------------- generic bf16 MFMA GEMM (128x128, BK=64)
__global__ __launch_bounds__(256) void mfma_gemm_kernel(
    const ushort* __restrict__ A1, const ushort* __restrict__ A2, int ksplit, int lda,
    const ushort* __restrict__ B, const float* __restrict__ bias,
    void* __restrict__ Cout, int store_bf16,
    int M, int N, int K, int ldc)
{
    __shared__ ushort As[128 * 64];
    __shared__ ushort Bs[128 * 64];
    int t = threadIdx.x;
    int m0 = blockIdx.x * 128, n0 = blockIdx.y * 128;
    int w = t >> 6, lane = t & 63;
    int q = lane >> 4, r = lane & 15;
    int wm = (w & 1) * 64, wn = (w >> 1) * 64;

    cfrag acc[4][4] = {};

    int srow_base = t >> 3;
    int skc = t & 7;

    for (int k0 = 0; k0 < K; k0 += 64) {
        const ushort* Ap; int kb;
        if (k0 < ksplit) { Ap = A1; kb = k0; } else { Ap = A2; kb = k0 - ksplit; }
        int4 av[4], bv[4];
        #pragma unroll
        for (int i = 0; i < 4; ++i) {
            int row = i * 32 + srow_base;
            int grow = m0 + row;
            av[i] = make_int4(0, 0, 0, 0);
            if (grow < M) av[i] = *(const int4*)(Ap + (size_t)grow * lda + kb + skc * 8);
            bv[i] = *(const int4*)(B + (size_t)(n0 + row) * K + k0 + skc * 8);
        }
        __syncthreads();
        #pragma unroll
        for (int i = 0; i < 4; ++i) {
            int row = i * 32 + srow_base;
            int off = row * 64 + ((skc ^ (row & 7)) * 8);
            *(int4*)&As[off] = av[i];
            *(int4*)&Bs[off] = bv[i];
        }
        __syncthreads();
        #pragma unroll
        for (int s = 0; s < 2; ++s) {
            bfrag af[4], bfr[4];
            int kc = s * 4 + q;
            #pragma unroll
            for (int mi = 0; mi < 4; ++mi) {
                int arow = wm + mi * 16 + r;
                af[mi] = *(const bfrag*)&As[arow * 64 + ((kc ^ (arow & 7)) * 8)];
            }
            #pragma unroll
            for (int ni = 0; ni < 4; ++ni) {
                int brow = wn + ni * 16 + r;
                bfr[ni] = *(const bfrag*)&Bs[brow * 64 + ((kc ^ (brow & 7)) * 8)];
            }
            #pragma unroll
            for (int mi = 0; mi < 4; ++mi)
                #pragma unroll
                for (int ni = 0; ni < 4; ++ni)
                    acc[mi][ni] = __builtin_amdgcn_mfma_f32_16x16x32_bf16(
                        af[mi], bfr[ni], acc[mi][ni], 0, 0, 0);
        }
    }

    float bvld[4];
    #pragma unroll
    for (int ni = 0; ni < 4; ++ni) bvld[ni] = bias[n0 + wn + ni * 16 + r];
    #pragma unroll
    for (int mi = 0; mi < 4; ++mi) {
        #pragma unroll
        for (int v = 0; v < 4; ++v) {
            int grow = m0 + wm + mi * 16 + q * 4 + v;
            if (grow >= M) continue;
            #pragma unroll
            for (int ni = 0; ni < 4; ++ni) {
                int gcol = n0 + wn + ni * 16 + r;
                if (gcol >= N) continue;
                float val = acc[mi][ni][v] + bvld[ni];
                if (store_bf16) ((ushort*)Cout)[(size_t)grow * ldc + gcol] = f2bf(val);
                else            ((float*)Cout)[(size_t)grow * ldc + gcol] = val;
            }
        }
    }
}

// ---------------------------------------------------------------- LN(20)+relu on npj32 [V,32] -> npj [V,20]
__global__ __launch_bounds__(256) void ln20_kernel(
    const float* __restrict__ npj32, const float* __restrict__ gp,
    const float* __restrict__ betap, float* __restrict__ npj, int V)
{
    int wid = threadIdx.x >> 6, j = threadIdx.x & 63;
    int v = blockIdx.x * 4 + wid;
    if (v >= V) return;
    float acc = (j < 20) ? npj32[(size_t)v * 32 + j] : 0.f;
    float s1 = acc, s2 = acc * acc;
    #pragma unroll
    for (int off = 32; off > 0; off >>= 1) {
        s1 += __shfl_xor(s1, off);
        s2 += __shfl_xor(s2, off);
    }
    float mu = s1 * (1.0f / 20.0f);
    float var = s2 * (1.0f / 20.0f) - mu * mu;
    if (j < 20) {
        float y = (acc - mu) * rsqrtf(var + 1e-5f) * gp[j] + betap[j];
        npj[(size_t)v * 20 + j] = fmaxf(y, 0.f);
    }
}

// ---------------------------------------------------------------- CSR build
__global__ __launch_bounds__(256) void deg_kernel(const int* __restrict__ dst, int* __restrict__ deg, int E) {
    int e = blockIdx.x * 256 + threadIdx.x;
    if (e < E) atomicAdd(&deg[dst[e]], 1);
}

__global__ __launch_bounds__(1024) void scan_kernel(const int* __restrict__ deg, int* __restrict__ row, int V) {
    __shared__ int wsum[16];
    __shared__ int carry_sh;
    int t = threadIdx.x, lane = t & 63, wid = t >> 6;
    if (t == 0) carry_sh = 0;
    __syncthreads();
    for (int base = 0; base < V; base += 1024) {
        int i = base + t;
        int val = (i < V) ? deg[i] : 0;
        #pragma unroll
        for (int s = 1; s < 64; s <<= 1) {
            int n = __shfl_up(val, s);
            if (lane >= s) val += n;
        }
        if (lane == 63) wsum[wid] = val;
        __syncthreads();
        if (wid == 0) {
            int x = (lane < 16) ? wsum[lane] : 0;
            #pragma unroll
            for (int s = 1; s < 16; s <<= 1) {
                int n = __shfl_up(x, s);
                if (lane >= s) x += n;
            }
            if (lane < 16) wsum[lane] = x;
        }
        __syncthreads();
        int wprefix = (wid > 0) ? wsum[wid - 1] : 0;
        int c = carry_sh;
        int incl = c + wprefix + val;
        if (i < V) row[i + 1] = incl;
        __syncthreads();
        if (t == 1023) carry_sh = incl;
    }
    if (t == 0) row[0] = 0;
}

__global__ __launch_bounds__(256) void scatter_kernel(
    const int* __restrict__ dst, const int* __restrict__ row,
    int* __restrict__ cnt, int* __restrict__ eorder, int E)
{
    int e = blockIdx.x * 256 + threadIdx.x;
    if (e < E) {
        int d = dst[e];
        int pos = row[d] + atomicAdd(&cnt[d], 1);
        eorder[pos] = e;
    }
}

// ---------------------------------------------------------------- per-node edge-logit projections
__global__ __launch_bounds__(256) void nodeproj_kernel(
    const float* __restrict__ nf, const float* __restrict__ We,
    float* __restrict__ pd, float* __restrict__ ps, int V)
{
    int wid = threadIdx.x >> 6, lane = threadIdx.x & 63;
    int v = blockIdx.x * 4 + wid;
    if (v >= V) return;
    const float* row = nf + (size_t)v * 256;
    int i = lane * 4;
    float4 x  = *(const float4*)(row + i);
    float4 wd = *(const float4*)(We + i);
    float4 wsv = *(const float4*)(We + 256 + i);
    float sd = x.x * wd.x + x.y * wd.y + x.z * wd.z + x.w * wd.w;
    float ss = x.x * wsv.x + x.y * wsv.y + x.z * wsv.z + x.w * wsv.w;
    #pragma unroll
    for (int off = 32; off > 0; off >>= 1) {
        sd += __shfl_xor(sd, off);
        ss += __shfl_xor(ss, off);
    }
    if (lane == 0) { pd[v] = sd; ps[v] = ss; }
}

// ---------------------------------------------------------------- edge prep (eorder order)
__global__ __launch_bounds__(256) void edgeprep_kernel(
    const int* __restrict__ eorder, const int* __restrict__ src, const int* __restrict__ dst,
    const float* __restrict__ pd, const float* __restrict__ ps, const float* __restrict__ be,
    float* __restrict__ logitOrd, int* __restrict__ srcOrd, int E)
{
    int p = blockIdx.x * 256 + threadIdx.x;
    if (p < E) {
        int e = eorder[p];
        int s = src[e], d = dst[e];
        srcOrd[p] = s;
        logitOrd[p] = fmaxf(pd[d] + ps[s] + be[0], 0.f);
    }
}

// ---------------------------------------------------------------- kron branch
// Stage 1 (block-coop): T_g[a][o] -> LDS bf16.  Stage 2: chunked LDS prefetch of edge npj
// vectors, wave-private edge loop: float4 sE reads + DPP (VALU-only) LN reductions.
__global__ __launch_bounds__(256) void kron_kernel(
    const float* __restrict__ npj, const int* __restrict__ srcOrd,
    const int* __restrict__ rowPtr,
    const float* __restrict__ Wk, const float* __restrict__ bk,
    const float* __restrict__ gkv, const float* __restrict__ betak,
    ushort* __restrict__ acat, int V)
{
    __shared__ __hip_bfloat16 T[KG * 20 * 256];   // 40 KB
    __shared__ float dsh[KG * 20];
    __shared__ float sE[KCHUNK * 20];             // 10 KB
    int t = threadIdx.x;
    int v0 = blockIdx.x * KG;

    if (t < KG * 20) {
        int g = t / 20, k = t % 20;
        int v = v0 + g;
        dsh[t] = (v < V) ? npj[(size_t)v * 20 + k] : 0.f;
    }
    __syncthreads();

    float dreg[KG][20];
    #pragma unroll
    for (int g = 0; g < KG; ++g)
        #pragma unroll
        for (int k = 0; k < 20; ++k) dreg[g][k] = dsh[g * 20 + k];

    for (int a = 0; a < 20; ++a) {
        float wv[20];
        #pragma unroll
        for (int k = 0; k < 20; ++k) wv[k] = Wk[(size_t)(a * 20 + k) * 256 + t];
        #pragma unroll
        for (int g = 0; g < KG; ++g) {
            float s = 0.f;
            #pragma unroll
            for (int k = 0; k < 20; ++k) s += dreg[g][k] * wv[k];
            T[(g * 20 + a) * 256 + t] = __float2bfloat16(s);
        }
    }
    __syncthreads();

    int wid = t >> 6, lane = t & 63;
    int v = v0 + wid;
    int c0 = lane * 4;

    float Tr[20][4];
    #pragma unroll
    for (int a = 0; a < 20; ++a) {
        const __hip_bfloat16* tp = &T[(wid * 20 + a) * 256 + c0];
        Tr[a][0] = __bfloat162float(tp[0]);
        Tr[a][1] = __bfloat162float(tp[1]);
        Tr[a][2] = __bfloat162float(tp[2]);
        Tr[a][3] = __bfloat162float(tp[3]);
    }
    float4 bkv = *(const float4*)(bk + c0);
    float4 gk4 = *(const float4*)(gkv + c0);
    float4 bt4 = *(const float4*)(betak + c0);

    int eBase = rowPtr[v0];
    int vEnd = (v0 + KG < V) ? (v0 + KG) : V;
    int eEndB = rowPtr[vEnd];
    int myE0 = (v < V) ? rowPtr[v] : 0;
    int myE1 = (v < V) ? rowPtr[v + 1] : 0;

    float a0 = 0.f, a1 = 0.f, a2 = 0.f, a3 = 0.f;

    for (int base = eBase; base < eEndB; base += KCHUNK) {
        int nC = eEndB - base; if (nC > KCHUNK) nC = KCHUNK;
        __syncthreads();   // previous chunk fully consumed
        for (int idx = t; idx < nC * 20; idx += 256) {
            int le = idx / 20, aa = idx - le * 20;
            sE[idx] = npj[(size_t)srcOrd[base + le] * 20 + aa];
        }
        __syncthreads();

        int lo = (myE0 > base) ? myE0 : base;
        int hi = (myE1 < base + nC) ? myE1 : base + nC;
        int p = lo;
        for (; p + 1 < hi; p += 2) {
            const float* sa = &sE[(p - base) * 20];
            const float* sb = &sE[(p + 1 - base) * 20];
            float4 sa0 = *(const float4*)(sa);
            float4 sa1 = *(const float4*)(sa + 4);
            float4 sa2 = *(const float4*)(sa + 8);
            float4 sa3 = *(const float4*)(sa + 12);
            float4 sa4 = *(const float4*)(sa + 16);
            float4 sb0 = *(const float4*)(sb);
            float4 sb1 = *(const float4*)(sb + 4);
            float4 sb2 = *(const float4*)(sb + 8);
            float4 sb3 = *(const float4*)(sb + 12);
            float4 sb4 = *(const float4*)(sb + 16);
            float sav[20] = {sa0.x, sa0.y, sa0.z, sa0.w, sa1.x, sa1.y, sa1.z, sa1.w,
                             sa2.x, sa2.y, sa2.z, sa2.w, sa3.x, sa3.y, sa3.z, sa3.w,
                             sa4.x, sa4.y, sa4.z, sa4.w};
            float sbv[20] = {sb0.x, sb0.y, sb0.z, sb0.w, sb1.x, sb1.y, sb1.z, sb1.w,
                             sb2.x, sb2.y, sb2.z, sb2.w, sb3.x, sb3.y, sb3.z, sb3.w,
                             sb4.x, sb4.y, sb4.z, sb4.w};
            float ya0 = bkv.x, ya1 = bkv.y, ya2 = bkv.z, ya3 = bkv.w;
            float yb0 = bkv.x, yb1 = bkv.y, yb2 = bkv.z, yb3 = bkv.w;
            #pragma unroll
            for (int a = 0; a < 20; ++a) {
                float va = sav[a], vb = sbv[a];
                ya0 += va * Tr[a][0]; ya1 += va * Tr[a][1];
                ya2 += va * Tr[a][2]; ya3 += va * Tr[a][3];
                yb0 += vb * Tr[a][0]; yb1 += vb * Tr[a][1];
                yb2 += vb * Tr[a][2]; yb3 += vb * Tr[a][3];
            }
            float s1a = dppWaveSum(ya0 + ya1 + ya2 + ya3);
            float s2a = dppWaveSum(ya0 * ya0 + ya1 * ya1 + ya2 * ya2 + ya3 * ya3);
            float s1b = dppWaveSum(yb0 + yb1 + yb2 + yb3);
            float s2b = dppWaveSum(yb0 * yb0 + yb1 * yb1 + yb2 * yb2 + yb3 * yb3);
            float mua = s1a * (1.0f / 256.0f);
            float rsa = rsqrtf(s2a * (1.0f / 256.0f) - mua * mua + 1e-5f);
            float mub = s1b * (1.0f / 256.0f);
            float rsb = rsqrtf(s2b * (1.0f / 256.0f) - mub * mub + 1e-5f);
            a0 += fmaxf((ya0 - mua) * rsa * gk4.x + bt4.x, 0.f) + fmaxf((yb0 - mub) * rsb * gk4.x + bt4.x, 0.f);
            a1 += fmaxf((ya1 - mua) * rsa * gk4.y + bt4.y, 0.f) + fmaxf((yb1 - mub) * rsb * gk4.y + bt4.y, 0.f);
            a2 += fmaxf((ya2 - mua) * rsa * gk4.z + bt4.z, 0.f) + fmaxf((yb2 - mub) * rsb * gk4.z + bt4.z, 0.f);
            a3 += fmaxf((ya3 - mua) * rsa * gk4.w + bt4.w, 0.f) + fmaxf((yb3 - mub) * rsb * gk4.w + bt4.w, 0.f);
        }
        if (p < hi) {
            const float* sa = &sE[(p - base) * 20];
            float4 sa0 = *(const float4*)(sa);
            float4 sa1 = *(const float4*)(sa + 4);
            float4 sa2 = *(const float4*)(sa + 8);
            float4 sa3 = *(const float4*)(sa + 12);
            float4 sa4 = *(const float4*)(sa + 16);
            float sav[20] = {sa0.x, sa0.y, sa0.z, sa0.w, sa1.x, sa1.y, sa1.z, sa1.w,
                             sa2.x, sa2.y, sa2.z, sa2.w, sa3.x, sa3.y, sa3.z, sa3.w,
                             sa4.x, sa4.y, sa4.z, sa4.w};
            float ya0 = bkv.x, ya1 = bkv.y, ya2 = bkv.z, ya3 = bkv.w;
            #pragma unroll
            for (int a = 0; a < 20; ++a) {
                float va = sav[a];
                ya0 += va * Tr[a][0]; ya1 += va * Tr[a][1];
                ya2 += va * Tr[a][2]; ya3 += va * Tr[a][3];
            }
            float s1a = dppWaveSum(ya0 + ya1 + ya2 + ya3);
            float s2a = dppWaveSum(ya0 * ya0 + ya1 * ya1 + ya2 * ya2 + ya3 * ya3);
            float mua = s1a * (1.0f / 256.0f);
            float rsa = rsqrtf(s2a * (1.0f / 256.0f) - mua * mua + 1e-5f);
            a0 += fmaxf((ya0 - mua) * rsa * gk4.x + bt4.x, 0.f);
            a1 += fmaxf((ya1 - mua) * rsa * gk4.y + bt4.y, 0.f);
            a2 += fmaxf((ya2 - mua) * rsa * gk4.z + bt4.z, 0.f);
            a3 += fmaxf((ya3 - mua) * rsa * gk4.w + bt4.w, 0.f);
        }
    }
    if (v < V) {
        ushort4 o;
        o.x = f2bf(a0); o.y = f2bf(a1); o.z = f2bf(a2); o.w = f2bf(a3);
        *(ushort4*)(acat + (size_t)v * 512 + 256 + c0) = o;
    }
}

// ---------------------------------------------------------------- attention stats per dst (linear reads)
__global__ __launch_bounds__(256) void att_kernel(
    const float* __restrict__ logitOrd, const int* __restrict__ rowPtr,
    float* __restrict__ mArr, float* __restrict__ invArr, int V)
{
    int wid = threadIdx.x >> 6, lane = threadIdx.x & 63;
    int v = blockIdx.x * 4 + wid;
    if (v >= V) return;
    int e0 = rowPtr[v], e1 = rowPtr[v + 1];
    float m = -1e30f;
    for (int p = e0 + lane; p < e1; p += 64) m = fmaxf(m, logitOrd[p]);
    #pragma unroll
    for (int off = 32; off > 0; off >>= 1) m = fmaxf(m, __shfl_xor(m, off));
    float d = 0.f;
    for (int p = e0 + lane; p < e1; p += 64) d += expf(logitOrd[p] - m);
    #pragma unroll
    for (int off = 32; off > 0; off >>= 1) d += __shfl_xor(d, off);
    if (lane == 0) {
        mArr[v] = m;
        invArr[v] = (e1 > e0) ? (1.0f / d) : 0.f;
    }
}

// ---------------------------------------------------------------- weighted context (bf16 hv, unroll x4)
__global__ __launch_bounds__(256) void ctx_kernel(
    const ushort* __restrict__ hv_bf, const float* __restrict__ logitOrd,
    const float* __restrict__ mArr, const float* __restrict__ invArr,
    const int* __restrict__ srcOrd, const int* __restrict__ rowPtr,
    ushort* __restrict__ ctx_bf, int V)
{
    int v = blockIdx.x;
    int t = threadIdx.x;
    int e0 = rowPtr[v], e1 = rowPtr[v + 1];
    float m = mArr[v], inv = invArr[v];
    float acc = 0.f;
    int p = e0;
    for (; p + 3 < e1; p += 4) {
        int s0 = srcOrd[p], s1 = srcOrd[p + 1], s2 = srcOrd[p + 2], s3 = srcOrd[p + 3];
        float w0 = expf(logitOrd[p] - m) * inv;
        float w1 = expf(logitOrd[p + 1] - m) * inv;
        float w2 = expf(logitOrd[p + 2] - m) * inv;
        float w3 = expf(logitOrd[p + 3] - m) * inv;
        float h0 = bf2f(hv_bf[(size_t)s0 * 256 + t]);
        float h1 = bf2f(hv_bf[(size_t)s1 * 256 + t]);
        float h2 = bf2f(hv_bf[(size_t)s2 * 256 + t]);
        float h3 = bf2f(hv_bf[(size_t)s3 * 256 + t]);
        acc += w0 * h0 + w1 * h1 + w2 * h2 + w3 * h3;
    }
    for (; p < e1; ++p) {
        float wgt = expf(logitOrd[p] - m) * inv;
        acc += wgt * bf2f(hv_bf[(size_t)srcOrd[p] * 256 + t]);
    }
    ctx_bf[(size_t)v * 256 + t] = f2bf(fmaxf(acc, 0.f));
}

// ---------------------------------------------------------------- GRU gates + LN -> bf16 into acat[:,0:256]
__global__ __launch_bounds__(256) void gru_ln_kernel(
    const ushort* __restrict__ rz, const ushort* __restrict__ inb,
    const ushort* __restrict__ hnb, const float* __restrict__ nf,
    const float* __restrict__ g_ln, const float* __restrict__ b_ln,
    ushort* __restrict__ acat, int V)
{
    __shared__ float red[8];
    int v = blockIdx.x, t = threadIdx.x;
    float r = sigmoidf(bf2f(rz[(size_t)v * 512 + t]));
    float z = sigmoidf(bf2f(rz[(size_t)v * 512 + 256 + t]));
    float n = tanhf(bf2f(inb[(size_t)v * 256 + t]) + r * bf2f(hnb[(size_t)v * 256 + t]));
    float h = (1.f - z) * n + z * nf[(size_t)v * 256 + t];
    float x = fmaxf(h, 0.f);
    float s1 = x, s2 = x * x;
    blockSum2(s1, s2, red);
    float mu = s1 * (1.0f / 256.0f);
    float var = s2 * (1.0f / 256.0f) - mu * mu;
    float y = (x - mu) * rsqrtf(var + 1e-5f) * g_ln[t] + b_ln[t];
    acat[(size_t)v * 512 + t] = f2bf(y);
}

// ---------------------------------------------------------------- row LayerNorm (optional relu)
__global__ __launch_bounds__(256) void ln_kernel(
    const float* __restrict__ in, float* __restrict__ out,
    const float* __restrict__ g, const float* __restrict__ b, int relu_after)
{
    __shared__ float red[8];
    int v = blockIdx.x, t = threadIdx.x;
    float x = in[(size_t)v * 256 + t];
    float s1 = x, s2 = x * x;
    blockSum2(s1, s2, red);
    float mu = s1 * (1.0f / 256.0f);
    float var = s2 * (1.0f / 256.0f) - mu * mu;
    float y = (x - mu) * rsqrtf(var + 1e-5f) * g[t] + b[t];
    if (relu_after) y = fmaxf(y, 0.f);
    out[(size_t)v * 256 + t] = y;
}

// ---------------------------------------------------------------- launcher
extern "C" void kernel_launch(void* const* d_in, const int* in_sizes, int n_in,
                              void* d_out, int out_size, void* d_ws, size_t ws_size,
                              hipStream_t stream)
{
    const float* nf    = (const float*)d_in[0];
    const int*   src   = (const int*)d_in[1];
    const int*   dst   = (const int*)d_in[2];
    const float* Wp    = (const float*)d_in[3];
    const float* bp    = (const float*)d_in[4];
    const float* gp    = (const float*)d_in[5];
    const float* betap = (const float*)d_in[6];
    const float* Wk    = (const float*)d_in[7];
    const float* bk    = (const float*)d_in[8];
    const float* gk    = (const float*)d_in[9];
    const float* betak = (const float*)d_in[10];
    const float* We    = (const float*)d_in[11];
    const float* be    = (const float*)d_in[12];
    const float* Wn    = (const float*)d_in[13];
    const float* bn    = (const float*)d_in[14];
    const float* W_ih  = (const float*)d_in[15];
    const float* W_hh  = (const float*)d_in[16];
    const float* b_ih  = (const float*)d_in[17];
    const float* b_hh  = (const float*)d_in[18];
    const float* g_ln  = (const float*)d_in[19];
    const float* bt_ln = (const float*)d_in[20];
    const float* Wc    = (const float*)d_in[21];
    const float* bc    = (const float*)d_in[22];
    const float* gc    = (const float*)d_in[23];
    const float* betac = (const float*)d_in[24];

    int V = in_sizes[0] / 256;
    int E = in_sizes[1];

    char* w = (char*)d_ws;
    auto alloc = [&](size_t bytes) -> char* {
        char* p = w;
        w += (bytes + 255) & ~(size_t)255;
        return p;
    };
    float*  npj      = (float*)alloc((size_t)V * 20 * 4);
    float*  npj32    = (float*)alloc((size_t)V * 32 * 4);
    ushort* acat     = (ushort*)alloc((size_t)V * 512 * 2);
    ushort* nf_bf    = (ushort*)alloc((size_t)V * 256 * 2);
    ushort* ctx_bf   = (ushort*)alloc((size_t)V * 256 * 2);
    ushort* rz_bf    = (ushort*)alloc((size_t)V * 512 * 2);
    ushort* hv_bf    = rz_bf;  // alias: hv dead before rz GEMM writes
    ushort* in_bf    = (ushort*)alloc((size_t)V * 256 * 2);
    ushort* hn_bf    = (ushort*)alloc((size_t)V * 256 * 2);
    ushort* BTn      = (ushort*)alloc(65536 * 2);
    ushort* BTrz     = (ushort*)alloc(262144 * 2);
    ushort* BTin     = (ushort*)alloc(65536 * 2);
    ushort* BThn     = (ushort*)alloc(65536 * 2);
    ushort* BTc      = (ushort*)alloc(131072 * 2);
    ushort* BTp      = (ushort*)alloc(32768 * 2);
    float*  bias_rz  = (float*)alloc(512 * 4);
    float*  bp_pad   = (float*)alloc(128 * 4);
    float*  logitOrd = (float*)alloc((size_t)E * 4);
    int*    srcOrd   = (int*)alloc((size_t)E * 4);
    float*  pd       = (float*)alloc((size_t)V * 4);
    float*  ps       = (float*)alloc((size_t)V * 4);
    float*  mArr     = (float*)alloc((size_t)V * 4);
    float*  invArr   = (float*)alloc((size_t)V * 4);
    int*    deg      = (int*)alloc((size_t)V * 4);
    int*    cnt      = (int*)alloc((size_t)V * 4);
    int*    rowp     = (int*)alloc((size_t)(V + 1) * 4);
    int*    eorder   = (int*)alloc((size_t)E * 4);

    hipMemsetAsync(deg, 0, (size_t)V * 4, stream);
    hipMemsetAsync(cnt, 0, (size_t)V * 4, stream);

    int mt = (V + 127) / 128;

    cast_bf16_kernel<<<(V * 64 + 255) / 256, 256, 0, stream>>>(nf, nf_bf, V * 256);
    prep_w_kernel<<<(623232 + 255) / 256, 256, 0, stream>>>(
        Wn, W_ih, W_hh, Wc, b_ih, b_hh, Wp, bp,
        BTn, BTrz, BTin, BThn, BTc, bias_rz, BTp, bp_pad);

    // npj32 = nf @ Wp + bp (N padded to 32, via 128-wide tile w/ zero rows)
    mfma_gemm_kernel<<<dim3(mt, 1), 256, 0, stream>>>(
        nf_bf, nf_bf, 256, 256, BTp, bp_pad, npj32, 0, V, 32, 256, 32);
    ln20_kernel<<<(V + 3) / 4, 256, 0, stream>>>(npj32, gp, betap, npj, V);

    deg_kernel<<<(E + 255) / 256, 256, 0, stream>>>(dst, deg, E);
    scan_kernel<<<1, 1024, 0, stream>>>(deg, rowp, V);
    scatter_kernel<<<(E + 255) / 256, 256, 0, stream>>>(dst, rowp, cnt, eorder, E);
    nodeproj_kernel<<<(V + 3) / 4, 256, 0, stream>>>(nf, We, pd, ps, V);
    edgeprep_kernel<<<(E + 255) / 256, 256, 0, stream>>>(
        eorder, src, dst, pd, ps, be, logitOrd, srcOrd, E);

    // hv = nf @ Wn + bn  -> bf16 (aliased on rz_bf; consumed by ctx before rz GEMM)
    mfma_gemm_kernel<<<dim3(mt, 2), 256, 0, stream>>>(
        nf_bf, nf_bf, 256, 256, BTn, bn, hv_bf, 1, V, 256, 256, 256);
    att_kernel<<<(V + 3) / 4, 256, 0, stream>>>(logitOrd, rowp, mArr, invArr, V);
    ctx_kernel<<<V, 256, 0, stream>>>(hv_bf, logitOrd, mArr, invArr, srcOrd, rowp, ctx_bf, V);

    kron_kernel<<<(V + KG - 1) / KG, 256, 0, stream>>>(
        npj, srcOrd, rowp, Wk, bk, gk, betak, acat, V);

    // rz = [ctx|nf] @ BTrz + (b_ih+b_hh)
    mfma_gemm_kernel<<<dim3(mt, 4), 256, 0, stream>>>(
        ctx_bf, nf_bf, 256, 256, BTrz, bias_rz, rz_bf, 1, V, 512, 512, 512);
    mfma_gemm_kernel<<<dim3(mt, 2), 256, 0, stream>>>(
        ctx_bf, ctx_bf, 256, 256, BTin, b_ih + 512, in_bf, 1, V, 256, 256, 256);
    mfma_gemm_kernel<<<dim3(mt, 2), 256, 0, stream>>>(
        nf_bf, nf_bf, 256, 256, BThn, b_hh + 512, hn_bf, 1, V, 256, 256, 256);

    gru_ln_kernel<<<V, 256, 0, stream>>>(rz_bf, in_bf, hn_bf, nf, g_ln, bt_ln, acat, V);

    mfma_gemm_kernel<<<dim3(mt, 2), 256, 0, stream>>>(
        acat, acat, 512, 512, BTc, bc, (float*)d_out, 0, V, 256, 512, 256);
    ln_kernel<<<V, 256, 0, stream>>>((float*)d_out, (float*)d_out, gc, betac, 1);
}